// Round 3
// baseline (1318.845 us; speedup 1.0000x reference)
//
#include <hip/hip_runtime.h>
#include <hip/hip_bf16.h>
#include <stdint.h>

#define BB 64
#define SS 2048
#define TT 128
#define GRP 6              // renorm interval AND em prefetch group (6*10.8 < 88.7 e-folds)

typedef __bf16 bf16x8 __attribute__((ext_vector_type(8)));
typedef float  f32x4  __attribute__((ext_vector_type(4)));

// LDS column swizzle for the transfer-matrix tile: element k of column n is
// stored at k ^ SWZ(n). Bits 3-6 => preserves 16B/8B/4B block contiguity and
// spreads the per-q bank groups so both b128 reads and b64 writes are balanced.
#define SWZ(n) (((n) & 15) << 3)

// Raw workgroup barrier that does NOT drain vmcnt (LDS ordering only):
// keeps the grouped em prefetch in flight across the per-step barrier.
__device__ __forceinline__ void wg_barrier_lds() {
    asm volatile("" ::: "memory");
    __builtin_amdgcn_s_waitcnt(0xc07f);   // lgkmcnt(0), vmcnt/expcnt no-wait
    __builtin_amdgcn_s_barrier();
    asm volatile("" ::: "memory");
}

// ---- bool-layout detection: mask[0,0] is always true (len >= 1024) ----
__device__ __forceinline__ int detect_mode(const void* maskp) {
    uint32_t w0 = ((const uint32_t*)maskp)[0];
    if (w0 == 1u) return 0;
    if (w0 == 0x3F800000u) return 2;
    if (w0 == 0x3F803F80u) return 3;
    return 1;
}
__device__ __forceinline__ int mask_at(const void* maskp, int mode, size_t idx) {
    if (mode == 0) return ((const int*)maskp)[idx] != 0;
    if (mode == 1) return ((const unsigned char*)maskp)[idx] != 0;
    if (mode == 2) return ((const float*)maskp)[idx] != 0.f;
    return ((const unsigned short*)maskp)[idx] != 0;
}

struct EndSh {
    __bf16 uS[2][TT];          // 512 B, double-buffered state
    float  wred[4];            // 16B-aligned at offset 512
    int    redi[8];
    double redd[8];
    int    redc[8];
    float  Minit;
};
struct MidSh {
    __bf16 T[2][128][128];     // 64 KiB, double-buffered transfer matrix (col-major, swizzled)
};
union ShU { EndSh e; MidSh m; };

// ---- 4-way split per batch ----
// blocks [0,64):    fwd matvec  alpha_0 -> alpha_q1          (A = E^T)
// blocks [64,128):  bwd matvec  delta_{len-1} -> gamma_q3    (A = E)
// blocks [128,256): transfer GEMM chain: seg=bid-128, b=seg>>1, half=seg&1
//                   half 0: T_A over (q1,q2]; half 1: T_B over (q2,q3]
// combine (comb_kernel): z = Cf+Cb+K1+K2 + log( gamma^T T_B T_A alpha ), f64.
__global__ __launch_bounds__(512) void scan_kernel(
    const float* __restrict__ em, const void* __restrict__ maskp,
    const int* __restrict__ tags, const void* __restrict__ forb,
    const float* __restrict__ trans,
    const float* __restrict__ startt, const float* __restrict__ endt,
    double* __restrict__ CdW, float* __restrict__ pendW,
    float* __restrict__ uMW, double* __restrict__ lsW,
    unsigned short* __restrict__ Tws, double* __restrict__ postout)
{
    const int t = threadIdx.x;
    const int w = t >> 6;          // wave 0..7
    const int lane = t & 63;
    const int q = lane >> 4;       // quad 0..3
    const int c = lane & 15;       // MFMA n-column
    const int bid = blockIdx.x;

    __shared__ __align__(16) ShU sh;

    const int mode = detect_mode(maskp);

    const bool isEnd = (bid < 2 * BB);
    const bool isF = (bid < BB);
    const int seg = isEnd ? 0 : (bid - 2 * BB);
    const int b = isEnd ? (isF ? bid : bid - BB) : (seg >> 1);
    const int half = seg & 1;

    // ---- length of this batch (contiguous mask prefix) ----
    {
        int cnt = 0;
        for (int s = t; s < SS; s += 512) cnt += mask_at(maskp, mode, (size_t)b * SS + s);
        #pragma unroll
        for (int off = 32; off >= 1; off >>= 1) cnt += __shfl_xor(cnt, off);
        if (lane == 0) sh.e.redi[w] = cnt;
    }
    __syncthreads();
    int len = 0;
    #pragma unroll
    for (int i = 0; i < 8; ++i) len += sh.e.redi[i];
    __syncthreads();   // everyone done reading redi before LDS reuse

    // ---- split points: ends ~1.35x cheaper per step than mids ----
    const int M  = ((len - 1) * 10) / 47;          // mid segment steps
    const int E1 = ((len - 1) - 2 * M + 1) >> 1;   // fwd steps
    const int q1 = E1;
    const int q2 = q1 + M;
    const int q3 = q2 + M;
    const int E2 = (len - 1) - q3;                 // bwd steps

    const float* emB = em + (size_t)b * SS * TT;

    if (isEnd) {
        // =================== END SEGMENTS (matvec chains) ===================
        // Round-2-proven structure; waves 4-7 duplicate waves 0-3 (identical
        // work, identical LDS writes) so the 512-thread barrier count matches.
        const int w4 = w & 3;
        const int steps = isF ? q1 : E2;

        // fwd: A[m=c][k=8q+jj] of tile (2w4+ml, kt) = E[32kt+8q+jj][32w4+16ml+c]
        // bwd: A[m=c][k=8q+jj] of tile (2w4+ml, kt) = E[32w4+16ml+c][32kt+8q+jj]
        bf16x8 afrag[2][4];
        #pragma unroll
        for (int ml = 0; ml < 2; ++ml) {
            #pragma unroll
            for (int kt = 0; kt < 4; ++kt) {
                #pragma unroll
                for (int jj = 0; jj < 8; ++jj) {
                    int row = isF ? (32 * kt + 8 * q + jj) : (32 * w4 + 16 * ml + c);
                    int col = isF ? (32 * w4 + 16 * ml + c) : (32 * kt + 8 * q + jj);
                    size_t idx = (size_t)row * TT + col;
                    afrag[ml][kt][jj] = mask_at(forb, mode, idx) ? (__bf16)0.f
                                                                 : (__bf16)__expf(trans[idx]);
                }
            }
        }

        // init: fwd u0 = exp(start + em[0] - M0); bwd d_{len-1} = exp(end + em[len-1] - M0)
        if (t < 16) {
            const float* base = isF ? startt : endt;
            const float* emI  = emB + (isF ? 0 : (size_t)(len - 1) * TT);
            float a[8]; float mx = -1e30f;
            #pragma unroll
            for (int jj = 0; jj < 8; ++jj) {
                int j = t * 8 + jj;
                a[jj] = base[j] + emI[j];
                mx = fmaxf(mx, a[jj]);
            }
            mx = fmaxf(mx, __shfl_xor(mx, 1)); mx = fmaxf(mx, __shfl_xor(mx, 2));
            mx = fmaxf(mx, __shfl_xor(mx, 4)); mx = fmaxf(mx, __shfl_xor(mx, 8));
            union { __bf16 h[8]; uint4 v; } pk;
            #pragma unroll
            for (int jj = 0; jj < 8; ++jj) pk.h[jj] = (__bf16)__expf(a[jj] - mx);
            *(uint4*)&sh.e.uS[0][t * 8] = pk.v;
            if (t == 0) sh.e.Minit = mx;
        }
        __syncthreads();

        double Cd = (double)sh.e.Minit;
        float pending = 1.0f;
        const int tag0 = 32 * w4 + 4 * q;
        const int tag1 = tag0 + 16;
        int cur = 0;

        auto stepfn = [&](float4 e0, float4 e1, bool ren, bool scaleEm) {
            const __bf16* ub = &sh.e.uS[cur][0];
            bf16x8 bf0 = *(const bf16x8*)(ub + 8 * q);
            bf16x8 bf1 = *(const bf16x8*)(ub + 32 + 8 * q);
            bf16x8 bf2 = *(const bf16x8*)(ub + 64 + 8 * q);
            bf16x8 bf3 = *(const bf16x8*)(ub + 96 + 8 * q);

            float sc00 = (scaleEm ? __expf(e0.x) : 1.0f) * pending;
            float sc01 = (scaleEm ? __expf(e0.y) : 1.0f) * pending;
            float sc02 = (scaleEm ? __expf(e0.z) : 1.0f) * pending;
            float sc03 = (scaleEm ? __expf(e0.w) : 1.0f) * pending;
            float sc10 = (scaleEm ? __expf(e1.x) : 1.0f) * pending;
            float sc11 = (scaleEm ? __expf(e1.y) : 1.0f) * pending;
            float sc12 = (scaleEm ? __expf(e1.z) : 1.0f) * pending;
            float sc13 = (scaleEm ? __expf(e1.w) : 1.0f) * pending;

            f32x4 aA0 = {0,0,0,0}, aB0 = {0,0,0,0}, aA1 = {0,0,0,0}, aB1 = {0,0,0,0};
            aA0 = __builtin_amdgcn_mfma_f32_16x16x32_bf16(afrag[0][0], bf0, aA0, 0, 0, 0);
            aA1 = __builtin_amdgcn_mfma_f32_16x16x32_bf16(afrag[1][0], bf0, aA1, 0, 0, 0);
            aB0 = __builtin_amdgcn_mfma_f32_16x16x32_bf16(afrag[0][2], bf2, aB0, 0, 0, 0);
            aB1 = __builtin_amdgcn_mfma_f32_16x16x32_bf16(afrag[1][2], bf2, aB1, 0, 0, 0);
            aA0 = __builtin_amdgcn_mfma_f32_16x16x32_bf16(afrag[0][1], bf1, aA0, 0, 0, 0);
            aA1 = __builtin_amdgcn_mfma_f32_16x16x32_bf16(afrag[1][1], bf1, aA1, 0, 0, 0);
            aB0 = __builtin_amdgcn_mfma_f32_16x16x32_bf16(afrag[0][3], bf3, aB0, 0, 0, 0);
            aB1 = __builtin_amdgcn_mfma_f32_16x16x32_bf16(afrag[1][3], bf3, aB1, 0, 0, 0);

            float v00 = (aA0[0] + aB0[0]) * sc00, v01 = (aA0[1] + aB0[1]) * sc01;
            float v02 = (aA0[2] + aB0[2]) * sc02, v03 = (aA0[3] + aB0[3]) * sc03;
            float v10 = (aA1[0] + aB1[0]) * sc10, v11 = (aA1[1] + aB1[1]) * sc11;
            float v12 = (aA1[2] + aB1[2]) * sc12, v13 = (aA1[3] + aB1[3]) * sc13;

            if (c == 0) {   // duplicate waves write identical values: benign
                union { __bf16 h[4]; uint2 v; } p0, p1;
                p0.h[0] = (__bf16)v00; p0.h[1] = (__bf16)v01;
                p0.h[2] = (__bf16)v02; p0.h[3] = (__bf16)v03;
                p1.h[0] = (__bf16)v10; p1.h[1] = (__bf16)v11;
                p1.h[2] = (__bf16)v12; p1.h[3] = (__bf16)v13;
                __bf16* un = &sh.e.uS[cur ^ 1][0];
                *(uint2*)(un + tag0) = p0.v;
                *(uint2*)(un + tag1) = p1.v;
            }
            if (ren) {
                float m = fmaxf(fmaxf(fmaxf(v00, v01), fmaxf(v02, v03)),
                                fmaxf(fmaxf(v10, v11), fmaxf(v12, v13)));
                m = fmaxf(m, __shfl_xor(m, 16));
                m = fmaxf(m, __shfl_xor(m, 32));
                if (lane == 0) sh.e.wred[w4] = m;
            }
            wg_barrier_lds();
            if (ren) {
                float4 wm = *(const float4*)sh.e.wred;
                float Mx = fmaxf(fmaxf(wm.x, wm.y), fmaxf(wm.z, wm.w));
                pending = 1.0f / Mx;
                Cd += (double)__logf(Mx);
            } else {
                pending = 1.0f;
            }
            cur ^= 1;
        };

        // em row at slot s: fwd -> 1+s; bwd -> len-2-s. Prefetch GRP ahead;
        // bwd issues loads in ascending-address order.
        int k = 0;
        float4 emc0[GRP], emc1[GRP];
        #pragma unroll
        for (int gg = 0; gg < GRP; ++gg) {
            int g = isF ? gg : (GRP - 1 - gg);
            int kk = isF ? (1 + g) : (len - 2 - g);
            kk = kk < SS ? kk : SS - 1;
            emc0[g] = *(const float4*)(emB + (size_t)kk * TT + tag0);
            emc1[g] = *(const float4*)(emB + (size_t)kk * TT + tag1);
        }

        while (k + GRP <= steps) {
            float4 emn0[GRP], emn1[GRP];
            #pragma unroll
            for (int gg = 0; gg < GRP; ++gg) {
                int g = isF ? gg : (GRP - 1 - gg);
                int kk = isF ? (1 + k + GRP + g) : (len - 2 - (k + GRP + g));
                kk = kk < SS ? kk : SS - 1;
                emn0[g] = *(const float4*)(emB + (size_t)kk * TT + tag0);
                emn1[g] = *(const float4*)(emB + (size_t)kk * TT + tag1);
            }
            #pragma unroll
            for (int g = 0; g < GRP; ++g)
                stepfn(emc0[g], emc1[g], g == GRP - 1, isF || (k + g != steps - 1));
            #pragma unroll
            for (int g = 0; g < GRP; ++g) { emc0[g] = emn0[g]; emc1[g] = emn1[g]; }
            k += GRP;
        }
        while (k < steps) {
            int kk = isF ? (1 + k) : (len - 2 - k);
            float4 e0 = *(const float4*)(emB + (size_t)kk * TT + tag0);
            float4 e1 = *(const float4*)(emB + (size_t)kk * TT + tag1);
            stepfn(e0, e1, true, isF || (k != steps - 1));
            ++k;
        }

        // ---- dump state (fwd: alpha_q1 scaled; bwd: gamma_q3 scaled) ----
        __syncthreads();
        if (t < TT) uMW[(size_t)(isF ? 0 : BB) * TT + (size_t)b * TT + t] = (float)sh.e.uS[cur][t];
        if (t == 0) { CdW[(isF ? 0 : BB) + b] = Cd; pendW[(isF ? 0 : BB) + b] = pending; }

        // ---- posterior path score (fwd blocks only; 512 threads strided) ----
        if (isF) {
            const int* tg = tags + (size_t)b * SS;
            double local = 0.0; int fcnt = 0;
            for (int kk = 1 + t; kk < len; kk += 512) {
                int tp = tg[kk - 1], tc = tg[kk];
                if (mask_at(forb, mode, (size_t)tp * TT + tc)) fcnt++;
                else local += (double)trans[tp * TT + tc];
                local += (double)emB[(size_t)kk * TT + tc];
            }
            if (t == 0) {
                local += (double)startt[tg[0]] + (double)emB[tg[0]];
                local += (double)endt[tg[len - 1]];
            }
            #pragma unroll
            for (int off = 32; off >= 1; off >>= 1) {
                local += __shfl_xor(local, off);
                fcnt  += __shfl_xor(fcnt, off);
            }
            if (lane == 0) { sh.e.redd[w] = local; sh.e.redc[w] = fcnt; }
            __syncthreads();
            if (t == 0) {
                double tot = 0.0; int fc = 0;
                #pragma unroll
                for (int i = 0; i < 8; ++i) { tot += sh.e.redd[i]; fc += sh.e.redc[i]; }
                postout[b] = tot - 100000.0 * (double)fc;
            }
        }
    } else {
        // =================== MID SEGMENTS (transfer-matrix GEMM chain) ===================
        // T stored col-major in LDS: T[buf][n][k^SWZ(n)] (bf16). Wave w owns
        // columns n = 16w..16w+15; lane (q,c): n = 16w+c.
        const int nc  = 16 * w + c;
        const int swz = SWZ(nc);
        const int ks  = half ? q2 : q1;     // steps consume em rows ks+1 .. ks+M
        const int steps = M;

        // A = E^T, all 8 m-tiles: af[mt][kt][jj] = E[32kt+8q+jj][16mt+c]
        bf16x8 af[8][4];
        #pragma unroll
        for (int mt = 0; mt < 8; ++mt) {
            #pragma unroll
            for (int kt = 0; kt < 4; ++kt) {
                #pragma unroll
                for (int jj = 0; jj < 8; ++jj) {
                    size_t idx = (size_t)(32 * kt + 8 * q + jj) * TT + (16 * mt + c);
                    af[mt][kt][jj] = mask_at(forb, mode, idx) ? (__bf16)0.f
                                                              : (__bf16)__expf(trans[idx]);
                }
            }
        }

        // identity init of T[0] (swizzled)
        for (int p = t; p < 8192; p += 512) {
            int n  = p >> 6;
            int k2 = (p & 63) * 2;
            unsigned int v = (k2 == n ? 0x3F80u : 0u) | (k2 + 1 == n ? 0x3F800000u : 0u);
            *(unsigned int*)&sh.m.T[0][n][k2 ^ SWZ(n)] = v;
        }
        __syncthreads();

        double Cdc = 0.0;
        float pendc = 1.0f;
        int cur = 0;

        // prologue em prefetch for k = ks+1
        float4 emc[8];
        #pragma unroll
        for (int mt = 0; mt < 8; ++mt)
            emc[mt] = *(const float4*)(emB + (size_t)(ks + 1) * TT + 16 * mt + 4 * q);

        for (int s = 0; s < steps; ++s) {
            const int k  = ks + 1 + s;
            const int kn = (k + 1 < SS) ? (k + 1) : (SS - 1);
            float4 emn[8];
            #pragma unroll
            for (int mt = 0; mt < 8; ++mt)
                emn[mt] = *(const float4*)(emB + (size_t)kn * TT + 16 * mt + 4 * q);

            // B-frags: B[k=8q+jj][n=c] of k-tile kt = T_cur[nc][32kt+8q+jj]
            bf16x8 bf[4];
            #pragma unroll
            for (int kt = 0; kt < 4; ++kt) {
                int eo = (32 * kt + 8 * q) ^ swz;
                bf[kt] = *(const bf16x8*)&sh.m.T[cur][nc][eo];
            }

            // row scales (overlap LDS wait)
            float sc[8][4];
            #pragma unroll
            for (int mt = 0; mt < 8; ++mt) {
                sc[mt][0] = __expf(emc[mt].x) * pendc;
                sc[mt][1] = __expf(emc[mt].y) * pendc;
                sc[mt][2] = __expf(emc[mt].z) * pendc;
                sc[mt][3] = __expf(emc[mt].w) * pendc;
            }

            f32x4 acc[8];
            #pragma unroll
            for (int mt = 0; mt < 8; ++mt) acc[mt] = (f32x4){0.f, 0.f, 0.f, 0.f};
            #pragma unroll
            for (int kt = 0; kt < 4; ++kt) {
                #pragma unroll
                for (int mt = 0; mt < 8; ++mt)
                    acc[mt] = __builtin_amdgcn_mfma_f32_16x16x32_bf16(af[mt][kt], bf[kt], acc[mt], 0, 0, 0);
            }

            const bool ren = ((s % GRP) == GRP - 1) || (s == steps - 1);
            float vm = 0.f;
            #pragma unroll
            for (int mt = 0; mt < 8; ++mt) {
                float v0 = acc[mt][0] * sc[mt][0], v1 = acc[mt][1] * sc[mt][1];
                float v2 = acc[mt][2] * sc[mt][2], v3 = acc[mt][3] * sc[mt][3];
                vm = fmaxf(vm, fmaxf(fmaxf(v0, v1), fmaxf(v2, v3)));
                union { __bf16 h[4]; uint2 u; } pk;
                pk.h[0] = (__bf16)v0; pk.h[1] = (__bf16)v1;
                pk.h[2] = (__bf16)v2; pk.h[3] = (__bf16)v3;
                int eo = (16 * mt + 4 * q) ^ swz;
                *(uint2*)&sh.m.T[cur ^ 1][nc][eo] = pk.u;
            }
            float Mc = 1.f;
            if (ren) {   // per-COLUMN max: reduce over q only -> fully in-wave
                vm = fmaxf(vm, __shfl_xor(vm, 16));
                vm = fmaxf(vm, __shfl_xor(vm, 32));
                Mc = vm;
            }
            wg_barrier_lds();
            if (ren) { pendc = 1.0f / Mc; Cdc += (double)__logf(Mc); }
            else     { pendc = 1.0f; }
            #pragma unroll
            for (int mt = 0; mt < 8; ++mt) emc[mt] = emn[mt];
            cur ^= 1;
        }

        __syncthreads();
        // per-column log-scale: true col = stored * exp(ls)
        if (lane < 16) lsW[(size_t)seg * 128 + 16 * w + lane] = Cdc + log((double)pendc);
        // dump T (unswizzle) to workspace, bf16 raw
        for (int p = t; p < 8192; p += 512) {
            int n  = p >> 6;
            int k2 = (p & 63) * 2;
            unsigned int v = *(const unsigned int*)&sh.m.T[cur][n][k2 ^ SWZ(n)];
            *(unsigned int*)&Tws[(size_t)seg * 16384 + (size_t)n * 128 + k2] = v;
        }
    }
}

// ---- combine: z[b] = Cf + lpf + K1 + K2 + Cb + lpb + log( sum_i s_i*gamma_i ) ----
__global__ __launch_bounds__(128) void comb_kernel(
    const double* __restrict__ CdW, const float* __restrict__ pendW,
    const float* __restrict__ uMW, const double* __restrict__ lsW,
    const unsigned short* __restrict__ Tws, double* __restrict__ zarr)
{
    const int b = blockIdx.x, i = threadIdx.x;
    __shared__ double wv[128];
    __shared__ double red[128];

    // stage 1: w_n = x_n * exp(lsA_n - K1)
    double lsA = lsW[(size_t)(2 * b) * 128 + i];
    float  xf  = uMW[(size_t)b * 128 + i];
    double a1  = (xf > 0.f) ? lsA + log((double)xf) : -1e300;
    red[i] = a1; __syncthreads();
    for (int sdel = 64; sdel >= 1; sdel >>= 1) {
        if (i < sdel) red[i] = fmax(red[i], red[i + sdel]);
        __syncthreads();
    }
    double K1 = red[0]; __syncthreads();
    wv[i] = (xf > 0.f) ? exp(a1 - K1) : 0.0; __syncthreads();

    const unsigned short* TA = Tws + (size_t)(2 * b) * 16384;
    double y = 0.0;
    for (int n = 0; n < 128; ++n) {
        unsigned int u = ((unsigned int)TA[(size_t)n * 128 + i]) << 16;
        y += (double)__uint_as_float(u) * wv[n];
    }
    __syncthreads();

    // stage 2: w2_n = y_n * exp(lsB_n - K2)
    double lsB = lsW[(size_t)(2 * b + 1) * 128 + i];
    double a2  = (y > 0.0) ? lsB + log(y) : -1e300;
    red[i] = a2; __syncthreads();
    for (int sdel = 64; sdel >= 1; sdel >>= 1) {
        if (i < sdel) red[i] = fmax(red[i], red[i + sdel]);
        __syncthreads();
    }
    double K2 = red[0]; __syncthreads();
    wv[i] = (y > 0.0) ? exp(a2 - K2) : 0.0; __syncthreads();

    const unsigned short* TB = Tws + (size_t)(2 * b + 1) * 16384;
    double s = 0.0;
    for (int n = 0; n < 128; ++n) {
        unsigned int u = ((unsigned int)TB[(size_t)n * 128 + i]) << 16;
        s += (double)__uint_as_float(u) * wv[n];
    }
    double g = (double)uMW[(size_t)(BB + b) * 128 + i];
    red[i] = s * g; __syncthreads();
    for (int sdel = 64; sdel >= 1; sdel >>= 1) {
        if (i < sdel) red[i] += red[i + sdel];
        __syncthreads();
    }
    if (i == 0) {
        zarr[b] = CdW[b] + log((double)pendW[b])
                + CdW[BB + b] + log((double)pendW[BB + b])
                + K1 + K2 + log(red[0]);
    }
}

// ---- nll = mean(post) - mean(z) ----
__global__ void fin_kernel(const double* __restrict__ z, const double* __restrict__ post,
                           float* __restrict__ out) {
    int t = threadIdx.x; // 64 threads, 1 wave
    double pv = post[t];
    double zv = z[t];
    #pragma unroll
    for (int off = 32; off >= 1; off >>= 1) {
        pv += __shfl_xor(pv, off);
        zv += __shfl_xor(zv, off);
    }
    if (t == 0) out[0] = (float)((pv - zv) / (double)BB);
}

extern "C" void kernel_launch(void* const* d_in, const int* in_sizes, int n_in,
                              void* d_out, int out_size, void* d_ws, size_t ws_size,
                              hipStream_t stream) {
    const float* em     = (const float*)d_in[0];
    const void*  maskp  = d_in[1];
    const int*   tags   = (const int*)d_in[2];
    const void*  forb   = d_in[3];
    const float* trans  = (const float*)d_in[4];
    const float* startt = (const float*)d_in[5];
    const float* endt   = (const float*)d_in[6];

    // workspace: ~4.4 MB
    double* post  = (double*)d_ws;                     // 64
    double* zarr  = post + BB;                         // 64
    double* CdW   = zarr + BB;                         // 128 (fwd | bwd)
    double* lsW   = CdW + 2 * BB;                      // 128 segs x 128 cols
    float*  pendW = (float*)(lsW + 128 * 128);         // 128
    float*  uMW   = pendW + 2 * BB;                    // 128 x 128 (fwd states | bwd states)
    unsigned short* Tws = (unsigned short*)(uMW + 128 * 128); // 128 segs x 128 x 128 bf16

    scan_kernel<<<4 * BB, 512, 0, stream>>>(em, maskp, tags, forb, trans, startt, endt,
                                            CdW, pendW, uMW, lsW, Tws, post);
    comb_kernel<<<BB, 128, 0, stream>>>(CdW, pendW, uMW, lsW, Tws, zarr);
    fin_kernel<<<1, 64, 0, stream>>>(zarr, post, (float*)d_out);
}

// Round 6
// 966.990 us; speedup vs baseline: 1.3639x; 1.3639x over previous
//
#include <hip/hip_runtime.h>
#include <hip/hip_bf16.h>
#include <stdint.h>

#define BB 64
#define SS 2048
#define TT 128
#define GRP 6              // renorm interval AND em prefetch group (7*10.8 < 88.7 e-folds worst lag)

typedef __bf16 bf16x8 __attribute__((ext_vector_type(8)));
typedef float  f32x4  __attribute__((ext_vector_type(4)));

// Raw workgroup barrier that does NOT drain vmcnt (LDS ordering only):
// keeps the grouped em prefetch in flight across the per-step barrier.
__device__ __forceinline__ void wg_barrier_lds() {
    asm volatile("" ::: "memory");
    __builtin_amdgcn_s_waitcnt(0xc07f);   // lgkmcnt(0), vmcnt/expcnt no-wait
    __builtin_amdgcn_s_barrier();
    asm volatile("" ::: "memory");
}

// ---- bool-layout detection: mask[0,0] is always true (len >= 1024) ----
__device__ __forceinline__ int detect_mode(const void* maskp) {
    uint32_t w0 = ((const uint32_t*)maskp)[0];
    if (w0 == 1u) return 0;
    if (w0 == 0x3F800000u) return 2;
    if (w0 == 0x3F803F80u) return 3;
    return 1;
}
__device__ __forceinline__ int mask_at(const void* maskp, int mode, size_t idx) {
    if (mode == 0) return ((const int*)maskp)[idx] != 0;
    if (mode == 1) return ((const unsigned char*)maskp)[idx] != 0;
    if (mode == 2) return ((const float*)maskp)[idx] != 0.f;
    return ((const unsigned short*)maskp)[idx] != 0;
}

struct EndSh {
    __bf16 uS[2][TT];          // 512 B, double-buffered state
    float  wred[4];            // 16B-aligned at offset 512
    int    redi[8];
    double redd[8];
    int    redc[8];
    float  Minit;
};
struct MidSh {
    // transfer matrix, col-major, XOR-swizzled: elem k of col n at n*128 + (k ^ ((n&7)<<3)).
    // 65,536 B total == the PROVEN round-3 LDS size (round-4's 70,688 B exceeded the
    // 64 KiB static __shared__ limit -> hard compile failure).
    __bf16 T[2][128 * 128];
};
union ShU { EndSh e; MidSh m; };

// ---- 4-way split per batch ----
// blocks [0,64):    fwd matvec  alpha_0 -> alpha_q1          (A = E^T)
// blocks [64,128):  bwd matvec  delta_{len-1} -> gamma_q3    (A = E)
// blocks [128,256): transfer GEMM chain: seg=bid-128, b=seg>>1, half=seg&1
//                   half 0: T_A over (q1,q2]; half 1: T_B over (q2,q3]
// combine (comb_kernel): z = Cf+Cb+K1+K2 + log( gamma^T T_B T_A alpha ), f64.
// __launch_bounds__(512, 2): 2 waves/SIMD min -> VGPR cap 256, no spill; legal on
// gfx950 (8 waves/CU at 256 VGPR each == the m69 occupancy point).
__global__ __launch_bounds__(512, 2) void scan_kernel(
    const float* __restrict__ em, const void* __restrict__ maskp,
    const int* __restrict__ tags, const void* __restrict__ forb,
    const float* __restrict__ trans,
    const float* __restrict__ startt, const float* __restrict__ endt,
    double* __restrict__ CdW, float* __restrict__ pendW,
    float* __restrict__ uMW, double* __restrict__ lsW,
    unsigned short* __restrict__ Tws, double* __restrict__ postout)
{
    const int t = threadIdx.x;
    const int w = t >> 6;          // wave 0..7
    const int lane = t & 63;
    const int q = lane >> 4;       // quad 0..3
    const int c = lane & 15;       // MFMA n-column
    const int bid = blockIdx.x;

    __shared__ __align__(16) ShU sh;

    const int mode = detect_mode(maskp);

    const bool isEnd = (bid < 2 * BB);
    const bool isF = (bid < BB);
    const int seg = isEnd ? 0 : (bid - 2 * BB);
    const int b = isEnd ? (isF ? bid : bid - BB) : (seg >> 1);
    const int half = seg & 1;

    // ---- length of this batch (contiguous mask prefix) ----
    {
        int cnt = 0;
        for (int s = t; s < SS; s += 512) cnt += mask_at(maskp, mode, (size_t)b * SS + s);
        #pragma unroll
        for (int off = 32; off >= 1; off >>= 1) cnt += __shfl_xor(cnt, off);
        if (lane == 0) sh.e.redi[w] = cnt;
    }
    __syncthreads();
    int len = 0;
    #pragma unroll
    for (int i = 0; i < 8; ++i) len += sh.e.redi[i];
    __syncthreads();   // everyone done reading redi before LDS reuse

    // ---- split points: mid step ~0.57x end step cost -> M = 0.32*(len-1) ----
    const int M  = ((len - 1) * 32) / 100;         // mid segment steps (each)
    const int E1 = ((len - 1) - 2 * M + 1) >> 1;   // fwd steps
    const int q1 = E1;
    const int q2 = q1 + M;
    const int q3 = q2 + M;
    const int E2 = (len - 1) - q3;                 // bwd steps

    const float* emB = em + (size_t)b * SS * TT;

    if (isEnd) {
        // =================== END SEGMENTS (matvec chains) ===================
        // Round-2/3-proven structure; waves 4-7 duplicate waves 0-3 (identical
        // work, identical LDS writes) so the 512-thread barrier count matches.
        const int w4 = w & 3;
        const int steps = isF ? q1 : E2;

        // fwd: A[m=c][k=8q+jj] of tile (2w4+ml, kt) = E[32kt+8q+jj][32w4+16ml+c]
        // bwd: A[m=c][k=8q+jj] of tile (2w4+ml, kt) = E[32w4+16ml+c][32kt+8q+jj]
        bf16x8 afrag[2][4];
        #pragma unroll
        for (int ml = 0; ml < 2; ++ml) {
            #pragma unroll
            for (int kt = 0; kt < 4; ++kt) {
                #pragma unroll
                for (int jj = 0; jj < 8; ++jj) {
                    int row = isF ? (32 * kt + 8 * q + jj) : (32 * w4 + 16 * ml + c);
                    int col = isF ? (32 * w4 + 16 * ml + c) : (32 * kt + 8 * q + jj);
                    size_t idx = (size_t)row * TT + col;
                    afrag[ml][kt][jj] = mask_at(forb, mode, idx) ? (__bf16)0.f
                                                                 : (__bf16)__expf(trans[idx]);
                }
            }
        }

        // init: fwd u0 = exp(start + em[0] - M0); bwd d_{len-1} = exp(end + em[len-1] - M0)
        if (t < 16) {
            const float* base = isF ? startt : endt;
            const float* emI  = emB + (isF ? 0 : (size_t)(len - 1) * TT);
            float a[8]; float mx = -1e30f;
            #pragma unroll
            for (int jj = 0; jj < 8; ++jj) {
                int j = t * 8 + jj;
                a[jj] = base[j] + emI[j];
                mx = fmaxf(mx, a[jj]);
            }
            mx = fmaxf(mx, __shfl_xor(mx, 1)); mx = fmaxf(mx, __shfl_xor(mx, 2));
            mx = fmaxf(mx, __shfl_xor(mx, 4)); mx = fmaxf(mx, __shfl_xor(mx, 8));
            union { __bf16 h[8]; uint4 v; } pk;
            #pragma unroll
            for (int jj = 0; jj < 8; ++jj) pk.h[jj] = (__bf16)__expf(a[jj] - mx);
            *(uint4*)&sh.e.uS[0][t * 8] = pk.v;
            if (t == 0) sh.e.Minit = mx;
        }
        __syncthreads();

        double Cd = (double)sh.e.Minit;
        float pending = 1.0f;
        const int tag0 = 32 * w4 + 4 * q;
        const int tag1 = tag0 + 16;
        int cur = 0;

        auto stepfn = [&](float4 e0, float4 e1, bool ren, bool scaleEm) {
            const __bf16* ub = &sh.e.uS[cur][0];
            bf16x8 bf0 = *(const bf16x8*)(ub + 8 * q);
            bf16x8 bf1 = *(const bf16x8*)(ub + 32 + 8 * q);
            bf16x8 bf2 = *(const bf16x8*)(ub + 64 + 8 * q);
            bf16x8 bf3 = *(const bf16x8*)(ub + 96 + 8 * q);

            float sc00 = (scaleEm ? __expf(e0.x) : 1.0f) * pending;
            float sc01 = (scaleEm ? __expf(e0.y) : 1.0f) * pending;
            float sc02 = (scaleEm ? __expf(e0.z) : 1.0f) * pending;
            float sc03 = (scaleEm ? __expf(e0.w) : 1.0f) * pending;
            float sc10 = (scaleEm ? __expf(e1.x) : 1.0f) * pending;
            float sc11 = (scaleEm ? __expf(e1.y) : 1.0f) * pending;
            float sc12 = (scaleEm ? __expf(e1.z) : 1.0f) * pending;
            float sc13 = (scaleEm ? __expf(e1.w) : 1.0f) * pending;

            f32x4 aA0 = {0,0,0,0}, aB0 = {0,0,0,0}, aA1 = {0,0,0,0}, aB1 = {0,0,0,0};
            aA0 = __builtin_amdgcn_mfma_f32_16x16x32_bf16(afrag[0][0], bf0, aA0, 0, 0, 0);
            aA1 = __builtin_amdgcn_mfma_f32_16x16x32_bf16(afrag[1][0], bf0, aA1, 0, 0, 0);
            aB0 = __builtin_amdgcn_mfma_f32_16x16x32_bf16(afrag[0][2], bf2, aB0, 0, 0, 0);
            aB1 = __builtin_amdgcn_mfma_f32_16x16x32_bf16(afrag[1][2], bf2, aB1, 0, 0, 0);
            aA0 = __builtin_amdgcn_mfma_f32_16x16x32_bf16(afrag[0][1], bf1, aA0, 0, 0, 0);
            aA1 = __builtin_amdgcn_mfma_f32_16x16x32_bf16(afrag[1][1], bf1, aA1, 0, 0, 0);
            aB0 = __builtin_amdgcn_mfma_f32_16x16x32_bf16(afrag[0][3], bf3, aB0, 0, 0, 0);
            aB1 = __builtin_amdgcn_mfma_f32_16x16x32_bf16(afrag[1][3], bf3, aB1, 0, 0, 0);

            float v00 = (aA0[0] + aB0[0]) * sc00, v01 = (aA0[1] + aB0[1]) * sc01;
            float v02 = (aA0[2] + aB0[2]) * sc02, v03 = (aA0[3] + aB0[3]) * sc03;
            float v10 = (aA1[0] + aB1[0]) * sc10, v11 = (aA1[1] + aB1[1]) * sc11;
            float v12 = (aA1[2] + aB1[2]) * sc12, v13 = (aA1[3] + aB1[3]) * sc13;

            if (c == 0) {   // duplicate waves write identical values: benign
                union { __bf16 h[4]; uint2 v; } p0, p1;
                p0.h[0] = (__bf16)v00; p0.h[1] = (__bf16)v01;
                p0.h[2] = (__bf16)v02; p0.h[3] = (__bf16)v03;
                p1.h[0] = (__bf16)v10; p1.h[1] = (__bf16)v11;
                p1.h[2] = (__bf16)v12; p1.h[3] = (__bf16)v13;
                __bf16* un = &sh.e.uS[cur ^ 1][0];
                *(uint2*)(un + tag0) = p0.v;
                *(uint2*)(un + tag1) = p1.v;
            }
            if (ren) {
                float m = fmaxf(fmaxf(fmaxf(v00, v01), fmaxf(v02, v03)),
                                fmaxf(fmaxf(v10, v11), fmaxf(v12, v13)));
                m = fmaxf(m, __shfl_xor(m, 16));
                m = fmaxf(m, __shfl_xor(m, 32));
                if (lane == 0) sh.e.wred[w4] = m;
            }
            wg_barrier_lds();
            if (ren) {
                float4 wm = *(const float4*)sh.e.wred;
                float Mx = fmaxf(fmaxf(wm.x, wm.y), fmaxf(wm.z, wm.w));
                pending = 1.0f / Mx;
                Cd += (double)__logf(Mx);
            } else {
                pending = 1.0f;
            }
            cur ^= 1;
        };

        // em row at slot s: fwd -> 1+s; bwd -> len-2-s. Prefetch GRP ahead.
        int k = 0;
        float4 emc0[GRP], emc1[GRP];
        #pragma unroll
        for (int gg = 0; gg < GRP; ++gg) {
            int g = isF ? gg : (GRP - 1 - gg);
            int kk = isF ? (1 + g) : (len - 2 - g);
            kk = kk < SS ? kk : SS - 1;
            kk = kk > 0 ? kk : 0;
            emc0[g] = *(const float4*)(emB + (size_t)kk * TT + tag0);
            emc1[g] = *(const float4*)(emB + (size_t)kk * TT + tag1);
        }

        while (k + GRP <= steps) {
            float4 emn0[GRP], emn1[GRP];
            #pragma unroll
            for (int gg = 0; gg < GRP; ++gg) {
                int g = isF ? gg : (GRP - 1 - gg);
                int kk = isF ? (1 + k + GRP + g) : (len - 2 - (k + GRP + g));
                kk = kk < SS ? kk : SS - 1;
                kk = kk > 0 ? kk : 0;
                emn0[g] = *(const float4*)(emB + (size_t)kk * TT + tag0);
                emn1[g] = *(const float4*)(emB + (size_t)kk * TT + tag1);
            }
            #pragma unroll
            for (int g = 0; g < GRP; ++g)
                stepfn(emc0[g], emc1[g], g == GRP - 1, isF || (k + g != steps - 1));
            #pragma unroll
            for (int g = 0; g < GRP; ++g) { emc0[g] = emn0[g]; emc1[g] = emn1[g]; }
            k += GRP;
        }
        while (k < steps) {
            int kk = isF ? (1 + k) : (len - 2 - k);
            float4 e0 = *(const float4*)(emB + (size_t)kk * TT + tag0);
            float4 e1 = *(const float4*)(emB + (size_t)kk * TT + tag1);
            stepfn(e0, e1, true, isF || (k != steps - 1));
            ++k;
        }

        // ---- dump state (fwd: alpha_q1 scaled; bwd: gamma_q3 scaled) ----
        __syncthreads();
        if (t < TT) uMW[(size_t)(isF ? 0 : BB) * TT + (size_t)b * TT + t] = (float)sh.e.uS[cur][t];
        if (t == 0) { CdW[(isF ? 0 : BB) + b] = Cd; pendW[(isF ? 0 : BB) + b] = pending; }

        // ---- posterior path score (fwd blocks only; 512 threads strided) ----
        if (isF) {
            const int* tg = tags + (size_t)b * SS;
            double local = 0.0; int fcnt = 0;
            for (int kk = 1 + t; kk < len; kk += 512) {
                int tp = tg[kk - 1], tc = tg[kk];
                if (mask_at(forb, mode, (size_t)tp * TT + tc)) fcnt++;
                else local += (double)trans[tp * TT + tc];
                local += (double)emB[(size_t)kk * TT + tc];
            }
            if (t == 0) {
                local += (double)startt[tg[0]] + (double)emB[tg[0]];
                local += (double)endt[tg[len - 1]];
            }
            #pragma unroll
            for (int off = 32; off >= 1; off >>= 1) {
                local += __shfl_xor(local, off);
                fcnt  += __shfl_xor(fcnt, off);
            }
            if (lane == 0) { sh.e.redd[w] = local; sh.e.redc[w] = fcnt; }
            __syncthreads();
            if (t == 0) {
                double tot = 0.0; int fc = 0;
                #pragma unroll
                for (int i = 0; i < 8; ++i) { tot += sh.e.redd[i]; fc += sh.e.redc[i]; }
                postout[b] = tot - 100000.0 * (double)fc;
            }
        }
    } else {
        // =================== MID SEGMENTS (transfer-matrix GEMM chain) ===================
        // Tiling: wave w = (wr = w>>2, wc = w&3); rows 64*wr..+63 (mt=4wr+mi),
        // cols 32*wc+c (ni=0) and +16 (ni=1). af = 4x4 frags = 64 VGPR (no spill).
        // XOR swizzle: elem k of col n at n*128 + (k ^ ((n&7)<<3)) ->
        // b128 reads: 8 lanes/16B-group (minimal); b64 writes: 4 lanes/8B-group (minimal).
        // Renorm: per-column max taken from the freshly LOADED B-frags (the full
        // column), fully in-wave; pend applied same-step, never carried.
        const int wr = w >> 2;
        const int wc = w & 3;
        const int ks = half ? q2 : q1;     // steps consume em rows ks+1 .. ks+M
        const int steps = M;
        const int col0 = 32 * wc + c;
        const int col1 = col0 + 16;
        const int base0 = col0 * 128;
        const int base1 = col1 * 128;
        const int sw = (c & 7) << 3;       // (col&7)<<3 — same for col0/col1
        const int rowq = 4 * q;

        // A = E^T: af[mi][kt][jj] = E[32kt+8q+jj][16*(4wr+mi)+c]
        bf16x8 af[4][4];
        #pragma unroll
        for (int mi = 0; mi < 4; ++mi) {
            #pragma unroll
            for (int kt = 0; kt < 4; ++kt) {
                #pragma unroll
                for (int jj = 0; jj < 8; ++jj) {
                    size_t idx = (size_t)(32 * kt + 8 * q + jj) * TT + (16 * (4 * wr + mi) + c);
                    af[mi][kt][jj] = mask_at(forb, mode, idx) ? (__bf16)0.f
                                                              : (__bf16)__expf(trans[idx]);
                }
            }
        }

        // identity init of T[0] (swizzled)
        for (int p = t; p < 8192; p += 512) {
            int n  = p >> 6;
            int k2 = (p & 63) * 2;
            unsigned int v = (k2 == n ? 0x3F80u : 0u) | (k2 + 1 == n ? 0x3F800000u : 0u);
            *(unsigned int*)&sh.m.T[0][n * 128 + (k2 ^ ((n & 7) << 3))] = v;
        }
        __syncthreads();

        double Cdc0 = 0.0, Cdc1 = 0.0;
        int cur = 0;
        int rc = 0;                        // steps since last renorm

        struct EmRow { float4 v[4]; };
        auto ldem = [&](int s) {
            EmRow r;
            int kk = ks + 1 + s; kk = kk < SS ? kk : SS - 1;
            #pragma unroll
            for (int mi = 0; mi < 4; ++mi)
                r.v[mi] = *(const float4*)(emB + (size_t)kk * TT + 16 * (4 * wr + mi) + rowq);
            return r;
        };

        auto midstep = [&](const EmRow& e) {
            const __bf16* Tc = &sh.m.T[cur][0];
            bf16x8 bf0[4], bf1[4];
            #pragma unroll
            for (int kt = 0; kt < 4; ++kt) {
                int eo = (32 * kt + 8 * q) ^ sw;
                bf0[kt] = *(const bf16x8*)(Tc + base0 + eo);
                bf1[kt] = *(const bf16x8*)(Tc + base1 + eo);
            }

            bool ren;
            if (rc == GRP) { ren = true; rc = 0; } else ren = false;
            ++rc;

            float pend0 = 1.0f, pend1 = 1.0f;
            if (ren) {    // per-column max of the INPUT, from the loaded frags
                float m0 = 0.f, m1 = 0.f;
                #pragma unroll
                for (int kt = 0; kt < 4; ++kt) {
                    #pragma unroll
                    for (int jj = 0; jj < 8; ++jj) {
                        m0 = fmaxf(m0, (float)bf0[kt][jj]);
                        m1 = fmaxf(m1, (float)bf1[kt][jj]);
                    }
                }
                m0 = fmaxf(m0, __shfl_xor(m0, 16)); m0 = fmaxf(m0, __shfl_xor(m0, 32));
                m1 = fmaxf(m1, __shfl_xor(m1, 16)); m1 = fmaxf(m1, __shfl_xor(m1, 32));
                pend0 = 1.0f / m0; pend1 = 1.0f / m1;
                Cdc0 += (double)__logf(m0); Cdc1 += (double)__logf(m1);
            }

            f32x4 acc[4][2];
            #pragma unroll
            for (int mi = 0; mi < 4; ++mi) {
                acc[mi][0] = (f32x4){0.f, 0.f, 0.f, 0.f};
                acc[mi][1] = (f32x4){0.f, 0.f, 0.f, 0.f};
            }
            #pragma unroll
            for (int kt = 0; kt < 4; ++kt) {
                #pragma unroll
                for (int mi = 0; mi < 4; ++mi)
                    acc[mi][0] = __builtin_amdgcn_mfma_f32_16x16x32_bf16(af[mi][kt], bf0[kt], acc[mi][0], 0, 0, 0);
                #pragma unroll
                for (int mi = 0; mi < 4; ++mi)
                    acc[mi][1] = __builtin_amdgcn_mfma_f32_16x16x32_bf16(af[mi][kt], bf1[kt], acc[mi][1], 0, 0, 0);
            }

            float sc[4][4];
            #pragma unroll
            for (int mi = 0; mi < 4; ++mi) {
                sc[mi][0] = __expf(e.v[mi].x); sc[mi][1] = __expf(e.v[mi].y);
                sc[mi][2] = __expf(e.v[mi].z); sc[mi][3] = __expf(e.v[mi].w);
            }

            __bf16* Tn = &sh.m.T[cur ^ 1][0];
            #pragma unroll
            for (int mi = 0; mi < 4; ++mi) {
                const int row = 16 * (4 * wr + mi) + rowq;
                const int eo = row ^ sw;
                union { __bf16 h[4]; uint2 u; } pk0, pk1;
                #pragma unroll
                for (int r = 0; r < 4; ++r) {
                    pk0.h[r] = (__bf16)(acc[mi][0][r] * sc[mi][r] * pend0);
                    pk1.h[r] = (__bf16)(acc[mi][1][r] * sc[mi][r] * pend1);
                }
                *(uint2*)(Tn + base0 + eo) = pk0.u;
                *(uint2*)(Tn + base1 + eo) = pk1.u;
            }
            wg_barrier_lds();
            cur ^= 1;
        };

        // 2-unrolled main loop with depth-2 em prefetch (named slots, rule-#20 safe)
        EmRow eA = ldem(0), eB = ldem(1);
        int s = 0;
        while (s + 2 <= steps) {
            midstep(eA); eA = ldem(s + 2);
            midstep(eB); eB = ldem(s + 3);
            s += 2;
        }
        if (s < steps) midstep(eA);

        __syncthreads();
        // per-column log-scale: true col = stored * exp(ls)
        if (wr == 0 && q == 0) {
            lsW[(size_t)seg * 128 + col0] = Cdc0;
            lsW[(size_t)seg * 128 + col1] = Cdc1;
        }
        // dump T (unswizzle) to workspace, bf16 raw
        for (int p = t; p < 8192; p += 512) {
            int n  = p >> 6;
            int k2 = (p & 63) * 2;
            unsigned int v = *(const unsigned int*)&sh.m.T[cur][n * 128 + (k2 ^ ((n & 7) << 3))];
            *(unsigned int*)&Tws[(size_t)seg * 16384 + (size_t)n * 128 + k2] = v;
        }
    }
}

// ---- combine: z[b] = Cf + lpf + K1 + K2 + Cb + lpb + log( sum_i s_i*gamma_i ) ----
__global__ __launch_bounds__(128) void comb_kernel(
    const double* __restrict__ CdW, const float* __restrict__ pendW,
    const float* __restrict__ uMW, const double* __restrict__ lsW,
    const unsigned short* __restrict__ Tws, double* __restrict__ zarr)
{
    const int b = blockIdx.x, i = threadIdx.x;
    __shared__ double wv[128];
    __shared__ double red[128];

    // stage 1: w_n = x_n * exp(lsA_n - K1)
    double lsA = lsW[(size_t)(2 * b) * 128 + i];
    float  xf  = uMW[(size_t)b * 128 + i];
    double a1  = (xf > 0.f) ? lsA + log((double)xf) : -1e300;
    red[i] = a1; __syncthreads();
    for (int sdel = 64; sdel >= 1; sdel >>= 1) {
        if (i < sdel) red[i] = fmax(red[i], red[i + sdel]);
        __syncthreads();
    }
    double K1 = red[0]; __syncthreads();
    wv[i] = (xf > 0.f) ? exp(a1 - K1) : 0.0; __syncthreads();

    const unsigned short* TA = Tws + (size_t)(2 * b) * 16384;
    double y = 0.0;
    for (int n = 0; n < 128; ++n) {
        unsigned int u = ((unsigned int)TA[(size_t)n * 128 + i]) << 16;
        y += (double)__uint_as_float(u) * wv[n];
    }
    __syncthreads();

    // stage 2: w2_n = y_n * exp(lsB_n - K2)
    double lsB = lsW[(size_t)(2 * b + 1) * 128 + i];
    double a2  = (y > 0.0) ? lsB + log(y) : -1e300;
    red[i] = a2; __syncthreads();
    for (int sdel = 64; sdel >= 1; sdel >>= 1) {
        if (i < sdel) red[i] = fmax(red[i], red[i + sdel]);
        __syncthreads();
    }
    double K2 = red[0]; __syncthreads();
    wv[i] = (y > 0.0) ? exp(a2 - K2) : 0.0; __syncthreads();

    const unsigned short* TB = Tws + (size_t)(2 * b + 1) * 16384;
    double s = 0.0;
    for (int n = 0; n < 128; ++n) {
        unsigned int u = ((unsigned int)TB[(size_t)n * 128 + i]) << 16;
        s += (double)__uint_as_float(u) * wv[n];
    }
    double g = (double)uMW[(size_t)(BB + b) * 128 + i];
    red[i] = s * g; __syncthreads();
    for (int sdel = 64; sdel >= 1; sdel >>= 1) {
        if (i < sdel) red[i] += red[i + sdel];
        __syncthreads();
    }
    if (i == 0) {
        zarr[b] = CdW[b] + log((double)pendW[b])
                + CdW[BB + b] + log((double)pendW[BB + b])
                + K1 + K2 + log(red[0]);
    }
}

// ---- nll = mean(post) - mean(z) ----
__global__ void fin_kernel(const double* __restrict__ z, const double* __restrict__ post,
                           float* __restrict__ out) {
    int t = threadIdx.x; // 64 threads, 1 wave
    double pv = post[t];
    double zv = z[t];
    #pragma unroll
    for (int off = 32; off >= 1; off >>= 1) {
        pv += __shfl_xor(pv, off);
        zv += __shfl_xor(zv, off);
    }
    if (t == 0) out[0] = (float)((pv - zv) / (double)BB);
}

extern "C" void kernel_launch(void* const* d_in, const int* in_sizes, int n_in,
                              void* d_out, int out_size, void* d_ws, size_t ws_size,
                              hipStream_t stream) {
    const float* em     = (const float*)d_in[0];
    const void*  maskp  = d_in[1];
    const int*   tags   = (const int*)d_in[2];
    const void*  forb   = d_in[3];
    const float* trans  = (const float*)d_in[4];
    const float* startt = (const float*)d_in[5];
    const float* endt   = (const float*)d_in[6];

    // workspace: ~4.4 MB (layout proven in round 3)
    double* post  = (double*)d_ws;                     // 64
    double* zarr  = post + BB;                         // 64
    double* CdW   = zarr + BB;                         // 128 (fwd | bwd)
    double* lsW   = CdW + 2 * BB;                      // 128 segs x 128 cols
    float*  pendW = (float*)(lsW + 128 * 128);         // 128
    float*  uMW   = pendW + 2 * BB;                    // 128 x 128 (fwd states | bwd states)
    unsigned short* Tws = (unsigned short*)(uMW + 128 * 128); // 128 segs x 128 x 128 bf16

    scan_kernel<<<4 * BB, 512, 0, stream>>>(em, maskp, tags, forb, trans, startt, endt,
                                            CdW, pendW, uMW, lsW, Tws, post);
    comb_kernel<<<BB, 128, 0, stream>>>(CdW, pendW, uMW, lsW, Tws, zarr);
    fin_kernel<<<1, 64, 0, stream>>>(zarr, post, (float*)d_out);
}

// Round 7
// 949.420 us; speedup vs baseline: 1.3891x; 1.0185x over previous
//
#include <hip/hip_runtime.h>
#include <hip/hip_bf16.h>
#include <stdint.h>

#define BB 64
#define SS 2048
#define TT 128
#define GRP 6              // renorm interval AND em prefetch group (7*10.8 < 88.7 e-folds worst lag)

typedef __bf16 bf16x8 __attribute__((ext_vector_type(8)));
typedef float  f32x4  __attribute__((ext_vector_type(4)));

// Raw workgroup barrier that does NOT drain vmcnt (LDS ordering only):
// keeps the grouped em prefetch in flight across the per-step barrier.
__device__ __forceinline__ void wg_barrier_lds() {
    asm volatile("" ::: "memory");
    __builtin_amdgcn_s_waitcnt(0xc07f);   // lgkmcnt(0), vmcnt/expcnt no-wait
    __builtin_amdgcn_s_barrier();
    asm volatile("" ::: "memory");
}

// ---- bool-layout detection: mask[0,0] is always true (len >= 1024) ----
__device__ __forceinline__ int detect_mode(const void* maskp) {
    uint32_t w0 = ((const uint32_t*)maskp)[0];
    if (w0 == 1u) return 0;
    if (w0 == 0x3F800000u) return 2;
    if (w0 == 0x3F803F80u) return 3;
    return 1;
}
__device__ __forceinline__ int mask_at(const void* maskp, int mode, size_t idx) {
    if (mode == 0) return ((const int*)maskp)[idx] != 0;
    if (mode == 1) return ((const unsigned char*)maskp)[idx] != 0;
    if (mode == 2) return ((const float*)maskp)[idx] != 0.f;
    return ((const unsigned short*)maskp)[idx] != 0;
}

struct EndSh {
    __bf16 uS[2][TT];          // 512 B, double-buffered state
    float  wred[4];            // 16B-aligned at offset 512
    int    redi[8];
    double redd[8];
    int    redc[8];
    float  Minit;
};
struct MidSh {
    // transfer matrix, col-major, XOR-swizzled: elem k of col n at n*128 + (k ^ ((n&7)<<3)).
    // 65,536 B total (the 64 KiB static __shared__ limit).
    __bf16 T[2][128 * 128];
};
union ShU { EndSh e; MidSh m; };

// ---- 4-way split per batch ----
// blocks [0,64):    fwd matvec  alpha_0 -> alpha_q1          (A = E^T)
// blocks [64,128):  bwd matvec  delta_{len-1} -> gamma_q3    (A = E)
// blocks [128,256): transfer GEMM chain: seg=bid-128, b=seg>>1, half=seg&1
//                   half 0: T_A over (q1,q2]; half 1: T_B over (q2,q3]
// combine (comb_kernel): z = Cf+Cb+K1+K2 + log( gamma^T T_B T_A alpha ), f64.
//
// __launch_bounds__(512, 1): min 1 wave/EU -> unified (VGPR+AGPR) budget 512/wave.
// Round 6 used (512,2) -> 256 unified budget -> compiler capped arch VGPRs at 116
// and MEMORY-SPILLED the mid path's per-step state (~1 GB HBM writes/dispatch,
// WRITE_SIZE counter). Grid is exactly 1 block/CU (256 blocks), so the occupancy
// this forgoes was never available anyway.
__global__ __launch_bounds__(512, 1) void scan_kernel(
    const float* __restrict__ em, const void* __restrict__ maskp,
    const int* __restrict__ tags, const void* __restrict__ forb,
    const float* __restrict__ trans,
    const float* __restrict__ startt, const float* __restrict__ endt,
    double* __restrict__ CdW, float* __restrict__ pendW,
    float* __restrict__ uMW, double* __restrict__ lsW,
    unsigned short* __restrict__ Tws, double* __restrict__ postout)
{
    const int t = threadIdx.x;
    const int w = t >> 6;          // wave 0..7
    const int lane = t & 63;
    const int q = lane >> 4;       // quad 0..3
    const int c = lane & 15;       // MFMA n-column
    const int bid = blockIdx.x;

    __shared__ __align__(16) ShU sh;

    const int mode = detect_mode(maskp);

    const bool isEnd = (bid < 2 * BB);
    const bool isF = (bid < BB);
    const int seg = isEnd ? 0 : (bid - 2 * BB);
    const int b = isEnd ? (isF ? bid : bid - BB) : (seg >> 1);
    const int half = seg & 1;

    // ---- length of this batch (contiguous mask prefix) ----
    {
        int cnt = 0;
        for (int s = t; s < SS; s += 512) cnt += mask_at(maskp, mode, (size_t)b * SS + s);
        #pragma unroll
        for (int off = 32; off >= 1; off >>= 1) cnt += __shfl_xor(cnt, off);
        if (lane == 0) sh.e.redi[w] = cnt;
    }
    __syncthreads();
    int len = 0;
    #pragma unroll
    for (int i = 0; i < 8; ++i) len += sh.e.redi[i];
    __syncthreads();   // everyone done reading redi before LDS reuse

    // ---- split points: mid step ~0.57x end step cost -> M = 0.32*(len-1) ----
    const int M  = ((len - 1) * 32) / 100;         // mid segment steps (each)
    const int E1 = ((len - 1) - 2 * M + 1) >> 1;   // fwd steps
    const int q1 = E1;
    const int q2 = q1 + M;
    const int q3 = q2 + M;
    const int E2 = (len - 1) - q3;                 // bwd steps

    const float* emB = em + (size_t)b * SS * TT;

    if (isEnd) {
        // =================== END SEGMENTS (matvec chains) ===================
        // Round-2/3-proven structure; waves 4-7 duplicate waves 0-3 (identical
        // work, identical LDS writes) so the 512-thread barrier count matches.
        const int w4 = w & 3;
        const int steps = isF ? q1 : E2;

        // fwd: A[m=c][k=8q+jj] of tile (2w4+ml, kt) = E[32kt+8q+jj][32w4+16ml+c]
        // bwd: A[m=c][k=8q+jj] of tile (2w4+ml, kt) = E[32w4+16ml+c][32kt+8q+jj]
        bf16x8 afrag[2][4];
        #pragma unroll
        for (int ml = 0; ml < 2; ++ml) {
            #pragma unroll
            for (int kt = 0; kt < 4; ++kt) {
                #pragma unroll
                for (int jj = 0; jj < 8; ++jj) {
                    int row = isF ? (32 * kt + 8 * q + jj) : (32 * w4 + 16 * ml + c);
                    int col = isF ? (32 * w4 + 16 * ml + c) : (32 * kt + 8 * q + jj);
                    size_t idx = (size_t)row * TT + col;
                    afrag[ml][kt][jj] = mask_at(forb, mode, idx) ? (__bf16)0.f
                                                                 : (__bf16)__expf(trans[idx]);
                }
            }
        }

        // init: fwd u0 = exp(start + em[0] - M0); bwd d_{len-1} = exp(end + em[len-1] - M0)
        if (t < 16) {
            const float* base = isF ? startt : endt;
            const float* emI  = emB + (isF ? 0 : (size_t)(len - 1) * TT);
            float a[8]; float mx = -1e30f;
            #pragma unroll
            for (int jj = 0; jj < 8; ++jj) {
                int j = t * 8 + jj;
                a[jj] = base[j] + emI[j];
                mx = fmaxf(mx, a[jj]);
            }
            mx = fmaxf(mx, __shfl_xor(mx, 1)); mx = fmaxf(mx, __shfl_xor(mx, 2));
            mx = fmaxf(mx, __shfl_xor(mx, 4)); mx = fmaxf(mx, __shfl_xor(mx, 8));
            union { __bf16 h[8]; uint4 v; } pk;
            #pragma unroll
            for (int jj = 0; jj < 8; ++jj) pk.h[jj] = (__bf16)__expf(a[jj] - mx);
            *(uint4*)&sh.e.uS[0][t * 8] = pk.v;
            if (t == 0) sh.e.Minit = mx;
        }
        __syncthreads();

        double Cd = (double)sh.e.Minit;
        float pending = 1.0f;
        const int tag0 = 32 * w4 + 4 * q;
        const int tag1 = tag0 + 16;
        int cur = 0;

        auto stepfn = [&](float4 e0, float4 e1, bool ren, bool scaleEm) {
            const __bf16* ub = &sh.e.uS[cur][0];
            bf16x8 bf0 = *(const bf16x8*)(ub + 8 * q);
            bf16x8 bf1 = *(const bf16x8*)(ub + 32 + 8 * q);
            bf16x8 bf2 = *(const bf16x8*)(ub + 64 + 8 * q);
            bf16x8 bf3 = *(const bf16x8*)(ub + 96 + 8 * q);

            float sc00 = (scaleEm ? __expf(e0.x) : 1.0f) * pending;
            float sc01 = (scaleEm ? __expf(e0.y) : 1.0f) * pending;
            float sc02 = (scaleEm ? __expf(e0.z) : 1.0f) * pending;
            float sc03 = (scaleEm ? __expf(e0.w) : 1.0f) * pending;
            float sc10 = (scaleEm ? __expf(e1.x) : 1.0f) * pending;
            float sc11 = (scaleEm ? __expf(e1.y) : 1.0f) * pending;
            float sc12 = (scaleEm ? __expf(e1.z) : 1.0f) * pending;
            float sc13 = (scaleEm ? __expf(e1.w) : 1.0f) * pending;

            f32x4 aA0 = {0,0,0,0}, aB0 = {0,0,0,0}, aA1 = {0,0,0,0}, aB1 = {0,0,0,0};
            aA0 = __builtin_amdgcn_mfma_f32_16x16x32_bf16(afrag[0][0], bf0, aA0, 0, 0, 0);
            aA1 = __builtin_amdgcn_mfma_f32_16x16x32_bf16(afrag[1][0], bf0, aA1, 0, 0, 0);
            aB0 = __builtin_amdgcn_mfma_f32_16x16x32_bf16(afrag[0][2], bf2, aB0, 0, 0, 0);
            aB1 = __builtin_amdgcn_mfma_f32_16x16x32_bf16(afrag[1][2], bf2, aB1, 0, 0, 0);
            aA0 = __builtin_amdgcn_mfma_f32_16x16x32_bf16(afrag[0][1], bf1, aA0, 0, 0, 0);
            aA1 = __builtin_amdgcn_mfma_f32_16x16x32_bf16(afrag[1][1], bf1, aA1, 0, 0, 0);
            aB0 = __builtin_amdgcn_mfma_f32_16x16x32_bf16(afrag[0][3], bf3, aB0, 0, 0, 0);
            aB1 = __builtin_amdgcn_mfma_f32_16x16x32_bf16(afrag[1][3], bf3, aB1, 0, 0, 0);

            float v00 = (aA0[0] + aB0[0]) * sc00, v01 = (aA0[1] + aB0[1]) * sc01;
            float v02 = (aA0[2] + aB0[2]) * sc02, v03 = (aA0[3] + aB0[3]) * sc03;
            float v10 = (aA1[0] + aB1[0]) * sc10, v11 = (aA1[1] + aB1[1]) * sc11;
            float v12 = (aA1[2] + aB1[2]) * sc12, v13 = (aA1[3] + aB1[3]) * sc13;

            if (c == 0) {   // duplicate waves write identical values: benign
                union { __bf16 h[4]; uint2 v; } p0, p1;
                p0.h[0] = (__bf16)v00; p0.h[1] = (__bf16)v01;
                p0.h[2] = (__bf16)v02; p0.h[3] = (__bf16)v03;
                p1.h[0] = (__bf16)v10; p1.h[1] = (__bf16)v11;
                p1.h[2] = (__bf16)v12; p1.h[3] = (__bf16)v13;
                __bf16* un = &sh.e.uS[cur ^ 1][0];
                *(uint2*)(un + tag0) = p0.v;
                *(uint2*)(un + tag1) = p1.v;
            }
            if (ren) {
                float m = fmaxf(fmaxf(fmaxf(v00, v01), fmaxf(v02, v03)),
                                fmaxf(fmaxf(v10, v11), fmaxf(v12, v13)));
                m = fmaxf(m, __shfl_xor(m, 16));
                m = fmaxf(m, __shfl_xor(m, 32));
                if (lane == 0) sh.e.wred[w4] = m;
            }
            wg_barrier_lds();
            if (ren) {
                float4 wm = *(const float4*)sh.e.wred;
                float Mx = fmaxf(fmaxf(wm.x, wm.y), fmaxf(wm.z, wm.w));
                pending = 1.0f / Mx;
                Cd += (double)__logf(Mx);
            } else {
                pending = 1.0f;
            }
            cur ^= 1;
        };

        // em row at slot s: fwd -> 1+s; bwd -> len-2-s. Prefetch GRP ahead.
        int k = 0;
        float4 emc0[GRP], emc1[GRP];
        #pragma unroll
        for (int gg = 0; gg < GRP; ++gg) {
            int g = isF ? gg : (GRP - 1 - gg);
            int kk = isF ? (1 + g) : (len - 2 - g);
            kk = kk < SS ? kk : SS - 1;
            kk = kk > 0 ? kk : 0;
            emc0[g] = *(const float4*)(emB + (size_t)kk * TT + tag0);
            emc1[g] = *(const float4*)(emB + (size_t)kk * TT + tag1);
        }

        while (k + GRP <= steps) {
            float4 emn0[GRP], emn1[GRP];
            #pragma unroll
            for (int gg = 0; gg < GRP; ++gg) {
                int g = isF ? gg : (GRP - 1 - gg);
                int kk = isF ? (1 + k + GRP + g) : (len - 2 - (k + GRP + g));
                kk = kk < SS ? kk : SS - 1;
                kk = kk > 0 ? kk : 0;
                emn0[g] = *(const float4*)(emB + (size_t)kk * TT + tag0);
                emn1[g] = *(const float4*)(emB + (size_t)kk * TT + tag1);
            }
            #pragma unroll
            for (int g = 0; g < GRP; ++g)
                stepfn(emc0[g], emc1[g], g == GRP - 1, isF || (k + g != steps - 1));
            #pragma unroll
            for (int g = 0; g < GRP; ++g) { emc0[g] = emn0[g]; emc1[g] = emn1[g]; }
            k += GRP;
        }
        while (k < steps) {
            int kk = isF ? (1 + k) : (len - 2 - k);
            float4 e0 = *(const float4*)(emB + (size_t)kk * TT + tag0);
            float4 e1 = *(const float4*)(emB + (size_t)kk * TT + tag1);
            stepfn(e0, e1, true, isF || (k != steps - 1));
            ++k;
        }

        // ---- dump state (fwd: alpha_q1 scaled; bwd: gamma_q3 scaled) ----
        __syncthreads();
        if (t < TT) uMW[(size_t)(isF ? 0 : BB) * TT + (size_t)b * TT + t] = (float)sh.e.uS[cur][t];
        if (t == 0) { CdW[(isF ? 0 : BB) + b] = Cd; pendW[(isF ? 0 : BB) + b] = pending; }

        // ---- posterior path score (fwd blocks only; 512 threads strided) ----
        if (isF) {
            const int* tg = tags + (size_t)b * SS;
            double local = 0.0; int fcnt = 0;
            for (int kk = 1 + t; kk < len; kk += 512) {
                int tp = tg[kk - 1], tc = tg[kk];
                if (mask_at(forb, mode, (size_t)tp * TT + tc)) fcnt++;
                else local += (double)trans[tp * TT + tc];
                local += (double)emB[(size_t)kk * TT + tc];
            }
            if (t == 0) {
                local += (double)startt[tg[0]] + (double)emB[tg[0]];
                local += (double)endt[tg[len - 1]];
            }
            #pragma unroll
            for (int off = 32; off >= 1; off >>= 1) {
                local += __shfl_xor(local, off);
                fcnt  += __shfl_xor(fcnt, off);
            }
            if (lane == 0) { sh.e.redd[w] = local; sh.e.redc[w] = fcnt; }
            __syncthreads();
            if (t == 0) {
                double tot = 0.0; int fc = 0;
                #pragma unroll
                for (int i = 0; i < 8; ++i) { tot += sh.e.redd[i]; fc += sh.e.redc[i]; }
                postout[b] = tot - 100000.0 * (double)fc;
            }
        }
    } else {
        // =================== MID SEGMENTS (transfer-matrix GEMM chain) ===================
        // Tiling: wave w = (wr = w>>2, wc = w&3); rows 64*wr..+63 (mt=4wr+mi),
        // cols 32*wc+c (ni=0) and +16 (ni=1). af = 4x4 frags = 64 VGPR.
        // XOR swizzle: elem k of col n at n*128 + (k ^ ((n&7)<<3)) ->
        // b128 reads: 8 lanes/16B-group (minimal); b64 writes: 4 lanes/8B-group (minimal).
        // Renorm: per-column max taken from the freshly LOADED B-frags (the full
        // column), fully in-wave; pend applied same-step, never carried.
        const int wr = w >> 2;
        const int wc = w & 3;
        const int ks = half ? q2 : q1;     // steps consume em rows ks+1 .. ks+M
        const int steps = M;
        const int col0 = 32 * wc + c;
        const int col1 = col0 + 16;
        const int base0 = col0 * 128;
        const int base1 = col1 * 128;
        const int sw = (c & 7) << 3;       // (col&7)<<3 — same for col0/col1
        const int rowq = 4 * q;

        // A = E^T: af[mi][kt][jj] = E[32kt+8q+jj][16*(4wr+mi)+c]
        bf16x8 af[4][4];
        #pragma unroll
        for (int mi = 0; mi < 4; ++mi) {
            #pragma unroll
            for (int kt = 0; kt < 4; ++kt) {
                #pragma unroll
                for (int jj = 0; jj < 8; ++jj) {
                    size_t idx = (size_t)(32 * kt + 8 * q + jj) * TT + (16 * (4 * wr + mi) + c);
                    af[mi][kt][jj] = mask_at(forb, mode, idx) ? (__bf16)0.f
                                                              : (__bf16)__expf(trans[idx]);
                }
            }
        }

        // identity init of T[0] (swizzled)
        for (int p = t; p < 8192; p += 512) {
            int n  = p >> 6;
            int k2 = (p & 63) * 2;
            unsigned int v = (k2 == n ? 0x3F80u : 0u) | (k2 + 1 == n ? 0x3F800000u : 0u);
            *(unsigned int*)&sh.m.T[0][n * 128 + (k2 ^ ((n & 7) << 3))] = v;
        }
        __syncthreads();

        double Cdc0 = 0.0, Cdc1 = 0.0;
        int cur = 0;
        int rc = 0;                        // steps since last renorm

        struct EmRow { float4 v[4]; };
        auto ldem = [&](int s) {
            EmRow r;
            int kk = ks + 1 + s; kk = kk < SS ? kk : SS - 1;
            #pragma unroll
            for (int mi = 0; mi < 4; ++mi)
                r.v[mi] = *(const float4*)(emB + (size_t)kk * TT + 16 * (4 * wr + mi) + rowq);
            return r;
        };

        auto midstep = [&](const EmRow& e) {
            const __bf16* Tc = &sh.m.T[cur][0];
            bf16x8 bf0[4], bf1[4];
            #pragma unroll
            for (int kt = 0; kt < 4; ++kt) {
                int eo = (32 * kt + 8 * q) ^ sw;
                bf0[kt] = *(const bf16x8*)(Tc + base0 + eo);
                bf1[kt] = *(const bf16x8*)(Tc + base1 + eo);
            }

            bool ren;
            if (rc == GRP) { ren = true; rc = 0; } else ren = false;
            ++rc;

            float pend0 = 1.0f, pend1 = 1.0f;
            if (ren) {    // per-column max of the INPUT, from the loaded frags
                float m0 = 0.f, m1 = 0.f;
                #pragma unroll
                for (int kt = 0; kt < 4; ++kt) {
                    #pragma unroll
                    for (int jj = 0; jj < 8; ++jj) {
                        m0 = fmaxf(m0, (float)bf0[kt][jj]);
                        m1 = fmaxf(m1, (float)bf1[kt][jj]);
                    }
                }
                m0 = fmaxf(m0, __shfl_xor(m0, 16)); m0 = fmaxf(m0, __shfl_xor(m0, 32));
                m1 = fmaxf(m1, __shfl_xor(m1, 16)); m1 = fmaxf(m1, __shfl_xor(m1, 32));
                pend0 = 1.0f / m0; pend1 = 1.0f / m1;
                Cdc0 += (double)__logf(m0); Cdc1 += (double)__logf(m1);
            }

            f32x4 acc[4][2];
            #pragma unroll
            for (int mi = 0; mi < 4; ++mi) {
                acc[mi][0] = (f32x4){0.f, 0.f, 0.f, 0.f};
                acc[mi][1] = (f32x4){0.f, 0.f, 0.f, 0.f};
            }
            #pragma unroll
            for (int kt = 0; kt < 4; ++kt) {
                #pragma unroll
                for (int mi = 0; mi < 4; ++mi)
                    acc[mi][0] = __builtin_amdgcn_mfma_f32_16x16x32_bf16(af[mi][kt], bf0[kt], acc[mi][0], 0, 0, 0);
                #pragma unroll
                for (int mi = 0; mi < 4; ++mi)
                    acc[mi][1] = __builtin_amdgcn_mfma_f32_16x16x32_bf16(af[mi][kt], bf1[kt], acc[mi][1], 0, 0, 0);
            }

            float sc[4][4];
            #pragma unroll
            for (int mi = 0; mi < 4; ++mi) {
                sc[mi][0] = __expf(e.v[mi].x); sc[mi][1] = __expf(e.v[mi].y);
                sc[mi][2] = __expf(e.v[mi].z); sc[mi][3] = __expf(e.v[mi].w);
            }

            __bf16* Tn = &sh.m.T[cur ^ 1][0];
            #pragma unroll
            for (int mi = 0; mi < 4; ++mi) {
                const int row = 16 * (4 * wr + mi) + rowq;
                const int eo = row ^ sw;
                union { __bf16 h[4]; uint2 u; } pk0, pk1;
                #pragma unroll
                for (int r = 0; r < 4; ++r) {
                    pk0.h[r] = (__bf16)(acc[mi][0][r] * sc[mi][r] * pend0);
                    pk1.h[r] = (__bf16)(acc[mi][1][r] * sc[mi][r] * pend1);
                }
                *(uint2*)(Tn + base0 + eo) = pk0.u;
                *(uint2*)(Tn + base1 + eo) = pk1.u;
            }
            wg_barrier_lds();
            cur ^= 1;
        };

        // 2-unrolled main loop with depth-2 em prefetch (named slots, rule-#20 safe)
        EmRow eA = ldem(0), eB = ldem(1);
        int s = 0;
        while (s + 2 <= steps) {
            midstep(eA); eA = ldem(s + 2);
            midstep(eB); eB = ldem(s + 3);
            s += 2;
        }
        if (s < steps) midstep(eA);

        __syncthreads();
        // per-column log-scale: true col = stored * exp(ls)
        if (wr == 0 && q == 0) {
            lsW[(size_t)seg * 128 + col0] = Cdc0;
            lsW[(size_t)seg * 128 + col1] = Cdc1;
        }
        // dump T (unswizzle) to workspace, bf16 raw
        for (int p = t; p < 8192; p += 512) {
            int n  = p >> 6;
            int k2 = (p & 63) * 2;
            unsigned int v = *(const unsigned int*)&sh.m.T[cur][n * 128 + (k2 ^ ((n & 7) << 3))];
            *(unsigned int*)&Tws[(size_t)seg * 16384 + (size_t)n * 128 + k2] = v;
        }
    }
}

// ---- combine: z[b] = Cf + lpf + K1 + K2 + Cb + lpb + log( sum_i s_i*gamma_i ) ----
__global__ __launch_bounds__(128) void comb_kernel(
    const double* __restrict__ CdW, const float* __restrict__ pendW,
    const float* __restrict__ uMW, const double* __restrict__ lsW,
    const unsigned short* __restrict__ Tws, double* __restrict__ zarr)
{
    const int b = blockIdx.x, i = threadIdx.x;
    __shared__ double wv[128];
    __shared__ double red[128];

    // stage 1: w_n = x_n * exp(lsA_n - K1)
    double lsA = lsW[(size_t)(2 * b) * 128 + i];
    float  xf  = uMW[(size_t)b * 128 + i];
    double a1  = (xf > 0.f) ? lsA + log((double)xf) : -1e300;
    red[i] = a1; __syncthreads();
    for (int sdel = 64; sdel >= 1; sdel >>= 1) {
        if (i < sdel) red[i] = fmax(red[i], red[i + sdel]);
        __syncthreads();
    }
    double K1 = red[0]; __syncthreads();
    wv[i] = (xf > 0.f) ? exp(a1 - K1) : 0.0; __syncthreads();

    const unsigned short* TA = Tws + (size_t)(2 * b) * 16384;
    double y = 0.0;
    for (int n = 0; n < 128; ++n) {
        unsigned int u = ((unsigned int)TA[(size_t)n * 128 + i]) << 16;
        y += (double)__uint_as_float(u) * wv[n];
    }
    __syncthreads();

    // stage 2: w2_n = y_n * exp(lsB_n - K2)
    double lsB = lsW[(size_t)(2 * b + 1) * 128 + i];
    double a2  = (y > 0.0) ? lsB + log(y) : -1e300;
    red[i] = a2; __syncthreads();
    for (int sdel = 64; sdel >= 1; sdel >>= 1) {
        if (i < sdel) red[i] = fmax(red[i], red[i + sdel]);
        __syncthreads();
    }
    double K2 = red[0]; __syncthreads();
    wv[i] = (y > 0.0) ? exp(a2 - K2) : 0.0; __syncthreads();

    const unsigned short* TB = Tws + (size_t)(2 * b + 1) * 16384;
    double s = 0.0;
    for (int n = 0; n < 128; ++n) {
        unsigned int u = ((unsigned int)TB[(size_t)n * 128 + i]) << 16;
        s += (double)__uint_as_float(u) * wv[n];
    }
    double g = (double)uMW[(size_t)(BB + b) * 128 + i];
    red[i] = s * g; __syncthreads();
    for (int sdel = 64; sdel >= 1; sdel >>= 1) {
        if (i < sdel) red[i] += red[i + sdel];
        __syncthreads();
    }
    if (i == 0) {
        zarr[b] = CdW[b] + log((double)pendW[b])
                + CdW[BB + b] + log((double)pendW[BB + b])
                + K1 + K2 + log(red[0]);
    }
}

// ---- nll = mean(post) - mean(z) ----
__global__ void fin_kernel(const double* __restrict__ z, const double* __restrict__ post,
                           float* __restrict__ out) {
    int t = threadIdx.x; // 64 threads, 1 wave
    double pv = post[t];
    double zv = z[t];
    #pragma unroll
    for (int off = 32; off >= 1; off >>= 1) {
        pv += __shfl_xor(pv, off);
        zv += __shfl_xor(zv, off);
    }
    if (t == 0) out[0] = (float)((pv - zv) / (double)BB);
}

extern "C" void kernel_launch(void* const* d_in, const int* in_sizes, int n_in,
                              void* d_out, int out_size, void* d_ws, size_t ws_size,
                              hipStream_t stream) {
    const float* em     = (const float*)d_in[0];
    const void*  maskp  = d_in[1];
    const int*   tags   = (const int*)d_in[2];
    const void*  forb   = d_in[3];
    const float* trans  = (const float*)d_in[4];
    const float* startt = (const float*)d_in[5];
    const float* endt   = (const float*)d_in[6];

    // workspace: ~4.4 MB (layout proven in round 3)
    double* post  = (double*)d_ws;                     // 64
    double* zarr  = post + BB;                         // 64
    double* CdW   = zarr + BB;                         // 128 (fwd | bwd)
    double* lsW   = CdW + 2 * BB;                      // 128 segs x 128 cols
    float*  pendW = (float*)(lsW + 128 * 128);         // 128
    float*  uMW   = pendW + 2 * BB;                    // 128 x 128 (fwd states | bwd states)
    unsigned short* Tws = (unsigned short*)(uMW + 128 * 128); // 128 segs x 128 x 128 bf16

    scan_kernel<<<4 * BB, 512, 0, stream>>>(em, maskp, tags, forb, trans, startt, endt,
                                            CdW, pendW, uMW, lsW, Tws, post);
    comb_kernel<<<BB, 128, 0, stream>>>(CdW, pendW, uMW, lsW, Tws, zarr);
    fin_kernel<<<1, 64, 0, stream>>>(zarr, post, (float*)d_out);
}

// Round 8
// 844.413 us; speedup vs baseline: 1.5618x; 1.1244x over previous
//
#include <hip/hip_runtime.h>
#include <hip/hip_bf16.h>
#include <stdint.h>

#define BB 64
#define SS 2048
#define TT 128
#define GRP 6              // renorm interval AND em prefetch group (7*10.8 < 88.7 e-folds worst lag)

typedef __bf16 bf16x8 __attribute__((ext_vector_type(8)));
typedef float  f32x4  __attribute__((ext_vector_type(4)));

// Raw workgroup barrier that does NOT drain vmcnt (LDS ordering only):
// keeps the grouped em prefetch in flight across the per-step barrier.
__device__ __forceinline__ void wg_barrier_lds() {
    asm volatile("" ::: "memory");
    __builtin_amdgcn_s_waitcnt(0xc07f);   // lgkmcnt(0), vmcnt/expcnt no-wait
    __builtin_amdgcn_s_barrier();
    asm volatile("" ::: "memory");
}

// ---- bool-layout detection: mask[0,0] is always true (len >= 1024) ----
__device__ __forceinline__ int detect_mode(const void* maskp) {
    uint32_t w0 = ((const uint32_t*)maskp)[0];
    if (w0 == 1u) return 0;
    if (w0 == 0x3F800000u) return 2;
    if (w0 == 0x3F803F80u) return 3;
    return 1;
}
__device__ __forceinline__ int mask_at(const void* maskp, int mode, size_t idx) {
    if (mode == 0) return ((const int*)maskp)[idx] != 0;
    if (mode == 1) return ((const unsigned char*)maskp)[idx] != 0;
    if (mode == 2) return ((const float*)maskp)[idx] != 0.f;
    return ((const unsigned short*)maskp)[idx] != 0;
}

struct EndSh {
    __bf16 uS[2][TT];          // 512 B, double-buffered state
    float  wred[4];            // 16B-aligned at offset 512
    int    redi[8];
    double redd[8];
    int    redc[8];
    float  Minit;
};
struct MidSh {
    // transfer matrix, col-major, XOR-swizzled: elem k of col n at n*128 + (k ^ ((n&7)<<3)).
    // 65,536 B total (the 64 KiB static __shared__ limit).
    __bf16 T[2][128 * 128];
};
union ShU { EndSh e; MidSh m; };

// ---- 4-way split per batch ----
// blocks [0,64):    fwd matvec  alpha_0 -> alpha_q1          (A = E^T)
// blocks [64,128):  bwd matvec  delta_{len-1} -> gamma_q3    (A = E)
// blocks [128,256): transfer GEMM chain: seg=bid-128, b=seg>>1, half=seg&1
//                   half 0: T_A over (q1,q2]; half 1: T_B over (q2,q3]
// combine (comb_kernel): z = Cf+Cb+K1+K2 + log( gamma^T T_B T_A alpha ), f64.
//
// RULE-#20 NOTE (the rounds-3..7 1-GB-write bug): every array here is indexed
// ONLY with compile-time constants (after unroll). Round 3 introduced
// `int g = isF ? gg : GRP-1-gg;` as a prefetch array index — a RUNTIME index —
// which turned emc0/emc1/emn0/emn1 into scratch allocas (~1 GB HBM writes per
// dispatch, unaffected by __launch_bounds__). Do not reintroduce.
__global__ __launch_bounds__(512, 1) void scan_kernel(
    const float* __restrict__ em, const void* __restrict__ maskp,
    const int* __restrict__ tags, const void* __restrict__ forb,
    const float* __restrict__ trans,
    const float* __restrict__ startt, const float* __restrict__ endt,
    double* __restrict__ CdW, float* __restrict__ pendW,
    float* __restrict__ uMW, double* __restrict__ lsW,
    unsigned short* __restrict__ Tws, double* __restrict__ postout)
{
    const int t = threadIdx.x;
    const int w = t >> 6;          // wave 0..7
    const int lane = t & 63;
    const int q = lane >> 4;       // quad 0..3
    const int c = lane & 15;       // MFMA n-column
    const int bid = blockIdx.x;

    __shared__ __align__(16) ShU sh;

    const int mode = detect_mode(maskp);

    const bool isEnd = (bid < 2 * BB);
    const bool isF = (bid < BB);
    const int seg = isEnd ? 0 : (bid - 2 * BB);
    const int b = isEnd ? (isF ? bid : bid - BB) : (seg >> 1);
    const int half = seg & 1;

    // ---- length of this batch (contiguous mask prefix) ----
    {
        int cnt = 0;
        for (int s = t; s < SS; s += 512) cnt += mask_at(maskp, mode, (size_t)b * SS + s);
        #pragma unroll
        for (int off = 32; off >= 1; off >>= 1) cnt += __shfl_xor(cnt, off);
        if (lane == 0) sh.e.redi[w] = cnt;
    }
    __syncthreads();
    int len = 0;
    #pragma unroll
    for (int i = 0; i < 8; ++i) len += sh.e.redi[i];
    __syncthreads();   // everyone done reading redi before LDS reuse

    // ---- split points: mid step ~0.57x end step cost -> M = 0.32*(len-1) ----
    const int M  = ((len - 1) * 32) / 100;         // mid segment steps (each)
    const int E1 = ((len - 1) - 2 * M + 1) >> 1;   // fwd steps
    const int q1 = E1;
    const int q2 = q1 + M;
    const int q3 = q2 + M;
    const int E2 = (len - 1) - q3;                 // bwd steps

    const float* emB = em + (size_t)b * SS * TT;

    if (isEnd) {
        // =================== END SEGMENTS (matvec chains) ===================
        // Round-2-proven structure (static prefetch indices); waves 4-7 duplicate
        // waves 0-3 so the 512-thread barrier count matches.
        const int w4 = w & 3;
        const int steps = isF ? q1 : E2;

        // fwd: A[m=c][k=8q+jj] of tile (2w4+ml, kt) = E[32kt+8q+jj][32w4+16ml+c]
        // bwd: A[m=c][k=8q+jj] of tile (2w4+ml, kt) = E[32w4+16ml+c][32kt+8q+jj]
        bf16x8 afrag[2][4];
        #pragma unroll
        for (int ml = 0; ml < 2; ++ml) {
            #pragma unroll
            for (int kt = 0; kt < 4; ++kt) {
                #pragma unroll
                for (int jj = 0; jj < 8; ++jj) {
                    int row = isF ? (32 * kt + 8 * q + jj) : (32 * w4 + 16 * ml + c);
                    int col = isF ? (32 * w4 + 16 * ml + c) : (32 * kt + 8 * q + jj);
                    size_t idx = (size_t)row * TT + col;
                    afrag[ml][kt][jj] = mask_at(forb, mode, idx) ? (__bf16)0.f
                                                                 : (__bf16)__expf(trans[idx]);
                }
            }
        }

        // init: fwd u0 = exp(start + em[0] - M0); bwd d_{len-1} = exp(end + em[len-1] - M0)
        if (t < 16) {
            const float* base = isF ? startt : endt;
            const float* emI  = emB + (isF ? 0 : (size_t)(len - 1) * TT);
            float a[8]; float mx = -1e30f;
            #pragma unroll
            for (int jj = 0; jj < 8; ++jj) {
                int j = t * 8 + jj;
                a[jj] = base[j] + emI[j];
                mx = fmaxf(mx, a[jj]);
            }
            mx = fmaxf(mx, __shfl_xor(mx, 1)); mx = fmaxf(mx, __shfl_xor(mx, 2));
            mx = fmaxf(mx, __shfl_xor(mx, 4)); mx = fmaxf(mx, __shfl_xor(mx, 8));
            union { __bf16 h[8]; uint4 v; } pk;
            #pragma unroll
            for (int jj = 0; jj < 8; ++jj) pk.h[jj] = (__bf16)__expf(a[jj] - mx);
            *(uint4*)&sh.e.uS[0][t * 8] = pk.v;
            if (t == 0) sh.e.Minit = mx;
        }
        __syncthreads();

        double Cd = (double)sh.e.Minit;
        float pending = 1.0f;
        const int tag0 = 32 * w4 + 4 * q;
        const int tag1 = tag0 + 16;
        int cur = 0;

        auto stepfn = [&](float4 e0, float4 e1, bool ren, bool scaleEm) {
            const __bf16* ub = &sh.e.uS[cur][0];
            bf16x8 bf0 = *(const bf16x8*)(ub + 8 * q);
            bf16x8 bf1 = *(const bf16x8*)(ub + 32 + 8 * q);
            bf16x8 bf2 = *(const bf16x8*)(ub + 64 + 8 * q);
            bf16x8 bf3 = *(const bf16x8*)(ub + 96 + 8 * q);

            float sc00 = (scaleEm ? __expf(e0.x) : 1.0f) * pending;
            float sc01 = (scaleEm ? __expf(e0.y) : 1.0f) * pending;
            float sc02 = (scaleEm ? __expf(e0.z) : 1.0f) * pending;
            float sc03 = (scaleEm ? __expf(e0.w) : 1.0f) * pending;
            float sc10 = (scaleEm ? __expf(e1.x) : 1.0f) * pending;
            float sc11 = (scaleEm ? __expf(e1.y) : 1.0f) * pending;
            float sc12 = (scaleEm ? __expf(e1.z) : 1.0f) * pending;
            float sc13 = (scaleEm ? __expf(e1.w) : 1.0f) * pending;

            f32x4 aA0 = {0,0,0,0}, aB0 = {0,0,0,0}, aA1 = {0,0,0,0}, aB1 = {0,0,0,0};
            aA0 = __builtin_amdgcn_mfma_f32_16x16x32_bf16(afrag[0][0], bf0, aA0, 0, 0, 0);
            aA1 = __builtin_amdgcn_mfma_f32_16x16x32_bf16(afrag[1][0], bf0, aA1, 0, 0, 0);
            aB0 = __builtin_amdgcn_mfma_f32_16x16x32_bf16(afrag[0][2], bf2, aB0, 0, 0, 0);
            aB1 = __builtin_amdgcn_mfma_f32_16x16x32_bf16(afrag[1][2], bf2, aB1, 0, 0, 0);
            aA0 = __builtin_amdgcn_mfma_f32_16x16x32_bf16(afrag[0][1], bf1, aA0, 0, 0, 0);
            aA1 = __builtin_amdgcn_mfma_f32_16x16x32_bf16(afrag[1][1], bf1, aA1, 0, 0, 0);
            aB0 = __builtin_amdgcn_mfma_f32_16x16x32_bf16(afrag[0][3], bf3, aB0, 0, 0, 0);
            aB1 = __builtin_amdgcn_mfma_f32_16x16x32_bf16(afrag[1][3], bf3, aB1, 0, 0, 0);

            float v00 = (aA0[0] + aB0[0]) * sc00, v01 = (aA0[1] + aB0[1]) * sc01;
            float v02 = (aA0[2] + aB0[2]) * sc02, v03 = (aA0[3] + aB0[3]) * sc03;
            float v10 = (aA1[0] + aB1[0]) * sc10, v11 = (aA1[1] + aB1[1]) * sc11;
            float v12 = (aA1[2] + aB1[2]) * sc12, v13 = (aA1[3] + aB1[3]) * sc13;

            if (c == 0) {   // duplicate waves write identical values: benign
                union { __bf16 h[4]; uint2 v; } p0, p1;
                p0.h[0] = (__bf16)v00; p0.h[1] = (__bf16)v01;
                p0.h[2] = (__bf16)v02; p0.h[3] = (__bf16)v03;
                p1.h[0] = (__bf16)v10; p1.h[1] = (__bf16)v11;
                p1.h[2] = (__bf16)v12; p1.h[3] = (__bf16)v13;
                __bf16* un = &sh.e.uS[cur ^ 1][0];
                *(uint2*)(un + tag0) = p0.v;
                *(uint2*)(un + tag1) = p1.v;
            }
            if (ren) {
                float m = fmaxf(fmaxf(fmaxf(v00, v01), fmaxf(v02, v03)),
                                fmaxf(fmaxf(v10, v11), fmaxf(v12, v13)));
                m = fmaxf(m, __shfl_xor(m, 16));
                m = fmaxf(m, __shfl_xor(m, 32));
                if (lane == 0) sh.e.wred[w4] = m;
            }
            wg_barrier_lds();
            if (ren) {
                float4 wm = *(const float4*)sh.e.wred;
                float Mx = fmaxf(fmaxf(wm.x, wm.y), fmaxf(wm.z, wm.w));
                pending = 1.0f / Mx;
                Cd += (double)__logf(Mx);
            } else {
                pending = 1.0f;
            }
            cur ^= 1;
        };

        // em row at slot s: fwd -> 1+s; bwd -> len-2-s. Prefetch GRP ahead.
        // STATIC array index g only (rule #20).
        int k = 0;
        float4 emc0[GRP], emc1[GRP];
        #pragma unroll
        for (int g = 0; g < GRP; ++g) {
            int kk = isF ? (1 + g) : (len - 2 - g);
            kk = kk < SS ? kk : SS - 1;
            kk = kk > 0 ? kk : 0;
            emc0[g] = *(const float4*)(emB + (size_t)kk * TT + tag0);
            emc1[g] = *(const float4*)(emB + (size_t)kk * TT + tag1);
        }

        while (k + GRP <= steps) {
            float4 emn0[GRP], emn1[GRP];
            #pragma unroll
            for (int g = 0; g < GRP; ++g) {
                int kk = isF ? (1 + k + GRP + g) : (len - 2 - (k + GRP + g));
                kk = kk < SS ? kk : SS - 1;
                kk = kk > 0 ? kk : 0;
                emn0[g] = *(const float4*)(emB + (size_t)kk * TT + tag0);
                emn1[g] = *(const float4*)(emB + (size_t)kk * TT + tag1);
            }
            #pragma unroll
            for (int g = 0; g < GRP; ++g)
                stepfn(emc0[g], emc1[g], g == GRP - 1, isF || (k + g != steps - 1));
            #pragma unroll
            for (int g = 0; g < GRP; ++g) { emc0[g] = emn0[g]; emc1[g] = emn1[g]; }
            k += GRP;
        }
        while (k < steps) {
            int kk = isF ? (1 + k) : (len - 2 - k);
            float4 e0 = *(const float4*)(emB + (size_t)kk * TT + tag0);
            float4 e1 = *(const float4*)(emB + (size_t)kk * TT + tag1);
            stepfn(e0, e1, true, isF || (k != steps - 1));
            ++k;
        }

        // ---- dump state (fwd: alpha_q1 scaled; bwd: gamma_q3 scaled) ----
        __syncthreads();
        if (t < TT) uMW[(size_t)(isF ? 0 : BB) * TT + (size_t)b * TT + t] = (float)sh.e.uS[cur][t];
        if (t == 0) { CdW[(isF ? 0 : BB) + b] = Cd; pendW[(isF ? 0 : BB) + b] = pending; }

        // ---- posterior path score (fwd blocks only; 512 threads strided) ----
        if (isF) {
            const int* tg = tags + (size_t)b * SS;
            double local = 0.0; int fcnt = 0;
            for (int kk = 1 + t; kk < len; kk += 512) {
                int tp = tg[kk - 1], tc = tg[kk];
                if (mask_at(forb, mode, (size_t)tp * TT + tc)) fcnt++;
                else local += (double)trans[tp * TT + tc];
                local += (double)emB[(size_t)kk * TT + tc];
            }
            if (t == 0) {
                local += (double)startt[tg[0]] + (double)emB[tg[0]];
                local += (double)endt[tg[len - 1]];
            }
            #pragma unroll
            for (int off = 32; off >= 1; off >>= 1) {
                local += __shfl_xor(local, off);
                fcnt  += __shfl_xor(fcnt, off);
            }
            if (lane == 0) { sh.e.redd[w] = local; sh.e.redc[w] = fcnt; }
            __syncthreads();
            if (t == 0) {
                double tot = 0.0; int fc = 0;
                #pragma unroll
                for (int i = 0; i < 8; ++i) { tot += sh.e.redd[i]; fc += sh.e.redc[i]; }
                postout[b] = tot - 100000.0 * (double)fc;
            }
        }
    } else {
        // =================== MID SEGMENTS (transfer-matrix GEMM chain) ===================
        // Tiling: wave w = (wr = w>>2, wc = w&3); rows 64*wr..+63 (mt=4wr+mi),
        // cols 32*wc+c (ni=0) and +16 (ni=1). af = 4x4 frags = 64 VGPR.
        // XOR swizzle: elem k of col n at n*128 + (k ^ ((n&7)<<3)).
        // Renorm: per-column max from the freshly LOADED B-frags, fully in-wave.
        const int wr = w >> 2;
        const int wc = w & 3;
        const int ks = half ? q2 : q1;     // steps consume em rows ks+1 .. ks+M
        const int steps = M;
        const int col0 = 32 * wc + c;
        const int col1 = col0 + 16;
        const int base0 = col0 * 128;
        const int base1 = col1 * 128;
        const int sw = (c & 7) << 3;       // (col&7)<<3 — same for col0/col1
        const int rowq = 4 * q;

        // A = E^T: af[mi][kt][jj] = E[32kt+8q+jj][16*(4wr+mi)+c]
        bf16x8 af[4][4];
        #pragma unroll
        for (int mi = 0; mi < 4; ++mi) {
            #pragma unroll
            for (int kt = 0; kt < 4; ++kt) {
                #pragma unroll
                for (int jj = 0; jj < 8; ++jj) {
                    size_t idx = (size_t)(32 * kt + 8 * q + jj) * TT + (16 * (4 * wr + mi) + c);
                    af[mi][kt][jj] = mask_at(forb, mode, idx) ? (__bf16)0.f
                                                              : (__bf16)__expf(trans[idx]);
                }
            }
        }

        // identity init of T[0] (swizzled)
        for (int p = t; p < 8192; p += 512) {
            int n  = p >> 6;
            int k2 = (p & 63) * 2;
            unsigned int v = (k2 == n ? 0x3F80u : 0u) | (k2 + 1 == n ? 0x3F800000u : 0u);
            *(unsigned int*)&sh.m.T[0][n * 128 + (k2 ^ ((n & 7) << 3))] = v;
        }
        __syncthreads();

        double Cdc0 = 0.0, Cdc1 = 0.0;
        int cur = 0;
        int rc = 0;                        // steps since last renorm

        // single-float4 em load: scalar return, no aggregate (rule #20 safe)
        auto lde = [&](int s, int mi) -> float4 {
            int kk = ks + 1 + s; kk = kk < SS ? kk : SS - 1;
            return *(const float4*)(emB + (size_t)kk * TT + 16 * (4 * wr + mi) + rowq);
        };

        auto midstep = [&](float4 ev0, float4 ev1, float4 ev2, float4 ev3) {
            const float4 ev[4] = {ev0, ev1, ev2, ev3};   // static-index only below
            const __bf16* Tc = &sh.m.T[cur][0];
            bf16x8 bf0[4], bf1[4];
            #pragma unroll
            for (int kt = 0; kt < 4; ++kt) {
                int eo = (32 * kt + 8 * q) ^ sw;
                bf0[kt] = *(const bf16x8*)(Tc + base0 + eo);
                bf1[kt] = *(const bf16x8*)(Tc + base1 + eo);
            }

            bool ren;
            if (rc == GRP) { ren = true; rc = 0; } else ren = false;
            ++rc;

            float pend0 = 1.0f, pend1 = 1.0f;
            if (ren) {    // per-column max of the INPUT, from the loaded frags
                float m0 = 0.f, m1 = 0.f;
                #pragma unroll
                for (int kt = 0; kt < 4; ++kt) {
                    #pragma unroll
                    for (int jj = 0; jj < 8; ++jj) {
                        m0 = fmaxf(m0, (float)bf0[kt][jj]);
                        m1 = fmaxf(m1, (float)bf1[kt][jj]);
                    }
                }
                m0 = fmaxf(m0, __shfl_xor(m0, 16)); m0 = fmaxf(m0, __shfl_xor(m0, 32));
                m1 = fmaxf(m1, __shfl_xor(m1, 16)); m1 = fmaxf(m1, __shfl_xor(m1, 32));
                pend0 = 1.0f / m0; pend1 = 1.0f / m1;
                Cdc0 += (double)__logf(m0); Cdc1 += (double)__logf(m1);
            }

            f32x4 acc[4][2];
            #pragma unroll
            for (int mi = 0; mi < 4; ++mi) {
                acc[mi][0] = (f32x4){0.f, 0.f, 0.f, 0.f};
                acc[mi][1] = (f32x4){0.f, 0.f, 0.f, 0.f};
            }
            #pragma unroll
            for (int kt = 0; kt < 4; ++kt) {
                #pragma unroll
                for (int mi = 0; mi < 4; ++mi)
                    acc[mi][0] = __builtin_amdgcn_mfma_f32_16x16x32_bf16(af[mi][kt], bf0[kt], acc[mi][0], 0, 0, 0);
                #pragma unroll
                for (int mi = 0; mi < 4; ++mi)
                    acc[mi][1] = __builtin_amdgcn_mfma_f32_16x16x32_bf16(af[mi][kt], bf1[kt], acc[mi][1], 0, 0, 0);
            }

            __bf16* Tn = &sh.m.T[cur ^ 1][0];
            #pragma unroll
            for (int mi = 0; mi < 4; ++mi) {
                float s0 = __expf(ev[mi].x), s1 = __expf(ev[mi].y);
                float s2 = __expf(ev[mi].z), s3 = __expf(ev[mi].w);
                const int row = 16 * (4 * wr + mi) + rowq;
                const int eo = row ^ sw;
                union { __bf16 h[4]; uint2 u; } pk0, pk1;
                pk0.h[0] = (__bf16)(acc[mi][0][0] * s0 * pend0);
                pk0.h[1] = (__bf16)(acc[mi][0][1] * s1 * pend0);
                pk0.h[2] = (__bf16)(acc[mi][0][2] * s2 * pend0);
                pk0.h[3] = (__bf16)(acc[mi][0][3] * s3 * pend0);
                pk1.h[0] = (__bf16)(acc[mi][1][0] * s0 * pend1);
                pk1.h[1] = (__bf16)(acc[mi][1][1] * s1 * pend1);
                pk1.h[2] = (__bf16)(acc[mi][1][2] * s2 * pend1);
                pk1.h[3] = (__bf16)(acc[mi][1][3] * s3 * pend1);
                *(uint2*)(Tn + base0 + eo) = pk0.u;
                *(uint2*)(Tn + base1 + eo) = pk1.u;
            }
            wg_barrier_lds();
            cur ^= 1;
        };

        // 2-unrolled main loop, depth-2 em prefetch in NAMED float4s (no arrays)
        float4 eA0 = lde(0, 0), eA1 = lde(0, 1), eA2 = lde(0, 2), eA3 = lde(0, 3);
        float4 eB0 = lde(1, 0), eB1 = lde(1, 1), eB2 = lde(1, 2), eB3 = lde(1, 3);
        int s = 0;
        while (s + 2 <= steps) {
            midstep(eA0, eA1, eA2, eA3);
            eA0 = lde(s + 2, 0); eA1 = lde(s + 2, 1); eA2 = lde(s + 2, 2); eA3 = lde(s + 2, 3);
            midstep(eB0, eB1, eB2, eB3);
            eB0 = lde(s + 3, 0); eB1 = lde(s + 3, 1); eB2 = lde(s + 3, 2); eB3 = lde(s + 3, 3);
            s += 2;
        }
        if (s < steps) midstep(eA0, eA1, eA2, eA3);

        __syncthreads();
        // per-column log-scale: true col = stored * exp(ls)
        if (wr == 0 && q == 0) {
            lsW[(size_t)seg * 128 + col0] = Cdc0;
            lsW[(size_t)seg * 128 + col1] = Cdc1;
        }
        // dump T (unswizzle) to workspace, bf16 raw
        for (int p = t; p < 8192; p += 512) {
            int n  = p >> 6;
            int k2 = (p & 63) * 2;
            unsigned int v = *(const unsigned int*)&sh.m.T[cur][n * 128 + (k2 ^ ((n & 7) << 3))];
            *(unsigned int*)&Tws[(size_t)seg * 16384 + (size_t)n * 128 + k2] = v;
        }
    }
}

// ---- combine: z[b] = Cf + lpf + K1 + K2 + Cb + lpb + log( sum_i s_i*gamma_i ) ----
__global__ __launch_bounds__(128) void comb_kernel(
    const double* __restrict__ CdW, const float* __restrict__ pendW,
    const float* __restrict__ uMW, const double* __restrict__ lsW,
    const unsigned short* __restrict__ Tws, double* __restrict__ zarr)
{
    const int b = blockIdx.x, i = threadIdx.x;
    __shared__ double wv[128];
    __shared__ double red[128];

    // stage 1: w_n = x_n * exp(lsA_n - K1)
    double lsA = lsW[(size_t)(2 * b) * 128 + i];
    float  xf  = uMW[(size_t)b * 128 + i];
    double a1  = (xf > 0.f) ? lsA + log((double)xf) : -1e300;
    red[i] = a1; __syncthreads();
    for (int sdel = 64; sdel >= 1; sdel >>= 1) {
        if (i < sdel) red[i] = fmax(red[i], red[i + sdel]);
        __syncthreads();
    }
    double K1 = red[0]; __syncthreads();
    wv[i] = (xf > 0.f) ? exp(a1 - K1) : 0.0; __syncthreads();

    const unsigned short* TA = Tws + (size_t)(2 * b) * 16384;
    double y = 0.0;
    for (int n = 0; n < 128; ++n) {
        unsigned int u = ((unsigned int)TA[(size_t)n * 128 + i]) << 16;
        y += (double)__uint_as_float(u) * wv[n];
    }
    __syncthreads();

    // stage 2: w2_n = y_n * exp(lsB_n - K2)
    double lsB = lsW[(size_t)(2 * b + 1) * 128 + i];
    double a2  = (y > 0.0) ? lsB + log(y) : -1e300;
    red[i] = a2; __syncthreads();
    for (int sdel = 64; sdel >= 1; sdel >>= 1) {
        if (i < sdel) red[i] = fmax(red[i], red[i + sdel]);
        __syncthreads();
    }
    double K2 = red[0]; __syncthreads();
    wv[i] = (y > 0.0) ? exp(a2 - K2) : 0.0; __syncthreads();

    const unsigned short* TB = Tws + (size_t)(2 * b + 1) * 16384;
    double s = 0.0;
    for (int n = 0; n < 128; ++n) {
        unsigned int u = ((unsigned int)TB[(size_t)n * 128 + i]) << 16;
        s += (double)__uint_as_float(u) * wv[n];
    }
    double g = (double)uMW[(size_t)(BB + b) * 128 + i];
    red[i] = s * g; __syncthreads();
    for (int sdel = 64; sdel >= 1; sdel >>= 1) {
        if (i < sdel) red[i] += red[i + sdel];
        __syncthreads();
    }
    if (i == 0) {
        zarr[b] = CdW[b] + log((double)pendW[b])
                + CdW[BB + b] + log((double)pendW[BB + b])
                + K1 + K2 + log(red[0]);
    }
}

// ---- nll = mean(post) - mean(z) ----
__global__ void fin_kernel(const double* __restrict__ z, const double* __restrict__ post,
                           float* __restrict__ out) {
    int t = threadIdx.x; // 64 threads, 1 wave
    double pv = post[t];
    double zv = z[t];
    #pragma unroll
    for (int off = 32; off >= 1; off >>= 1) {
        pv += __shfl_xor(pv, off);
        zv += __shfl_xor(zv, off);
    }
    if (t == 0) out[0] = (float)((pv - zv) / (double)BB);
}

extern "C" void kernel_launch(void* const* d_in, const int* in_sizes, int n_in,
                              void* d_out, int out_size, void* d_ws, size_t ws_size,
                              hipStream_t stream) {
    const float* em     = (const float*)d_in[0];
    const void*  maskp  = d_in[1];
    const int*   tags   = (const int*)d_in[2];
    const void*  forb   = d_in[3];
    const float* trans  = (const float*)d_in[4];
    const float* startt = (const float*)d_in[5];
    const float* endt   = (const float*)d_in[6];

    // workspace: ~4.4 MB (layout proven in round 3)
    double* post  = (double*)d_ws;                     // 64
    double* zarr  = post + BB;                         // 64
    double* CdW   = zarr + BB;                         // 128 (fwd | bwd)
    double* lsW   = CdW + 2 * BB;                      // 128 segs x 128 cols
    float*  pendW = (float*)(lsW + 128 * 128);         // 128
    float*  uMW   = pendW + 2 * BB;                    // 128 x 128 (fwd states | bwd states)
    unsigned short* Tws = (unsigned short*)(uMW + 128 * 128); // 128 segs x 128 x 128 bf16

    scan_kernel<<<4 * BB, 512, 0, stream>>>(em, maskp, tags, forb, trans, startt, endt,
                                            CdW, pendW, uMW, lsW, Tws, post);
    comb_kernel<<<BB, 128, 0, stream>>>(CdW, pendW, uMW, lsW, Tws, zarr);
    fin_kernel<<<1, 64, 0, stream>>>(zarr, post, (float*)d_out);
}

// Round 9
// 427.990 us; speedup vs baseline: 3.0815x; 1.9730x over previous
//
#include <hip/hip_runtime.h>
#include <hip/hip_bf16.h>
#include <stdint.h>

#define BB 64
#define SS 2048
#define TT 128
#define GRP 6              // renorm interval AND em prefetch group (7*10.8 < 88.7 e-folds worst lag)

typedef __bf16 bf16x8 __attribute__((ext_vector_type(8)));
typedef float  f32x4  __attribute__((ext_vector_type(4)));

// Raw workgroup barrier that does NOT drain vmcnt (LDS ordering only):
// keeps the grouped em prefetch in flight across the per-step barrier.
__device__ __forceinline__ void wg_barrier_lds() {
    asm volatile("" ::: "memory");
    __builtin_amdgcn_s_waitcnt(0xc07f);   // lgkmcnt(0), vmcnt/expcnt no-wait
    __builtin_amdgcn_s_barrier();
    asm volatile("" ::: "memory");
}

// ---- bool-layout detection: mask[0,0] is always true (len >= 1024) ----
__device__ __forceinline__ int detect_mode(const void* maskp) {
    uint32_t w0 = ((const uint32_t*)maskp)[0];
    if (w0 == 1u) return 0;
    if (w0 == 0x3F800000u) return 2;
    if (w0 == 0x3F803F80u) return 3;
    return 1;
}
__device__ __forceinline__ int mask_at(const void* maskp, int mode, size_t idx) {
    if (mode == 0) return ((const int*)maskp)[idx] != 0;
    if (mode == 1) return ((const unsigned char*)maskp)[idx] != 0;
    if (mode == 2) return ((const float*)maskp)[idx] != 0.f;
    return ((const unsigned short*)maskp)[idx] != 0;
}

struct EndSh {
    __bf16 uS[2][TT];          // 512 B, double-buffered state
    float  wred[4];            // 16B-aligned at offset 512
    int    redi[8];
    double redd[8];
    int    redc[8];
    float  Minit;
};
struct MidSh {
    // transfer matrix, col-major, XOR-swizzled: elem k of col n at n*128 + (k ^ ((n&7)<<3)).
    // 65,536 B total (the 64 KiB static __shared__ limit).
    __bf16 T[2][128 * 128];
};
union ShU { EndSh e; MidSh m; };

// ---- 4-way split per batch ----
// blocks [0,64):    fwd matvec  alpha_0 -> alpha_q1          (A = E^T)
// blocks [64,128):  bwd matvec  delta_{len-1} -> gamma_q3    (A = E)
// blocks [128,256): transfer GEMM chain: seg=bid-128, b=seg>>1, half=seg&1
//                   half 0: T_A over (q1,q2]; half 1: T_B over (q2,q3]
// combine (comb_kernel): z = Cf+Cb+K1+K2 + log( gamma^T T_B T_A alpha ), f64.
//
// Cost model (round-8 counters): mid step ~1200 ns (LDS-pipe-bound: 96 KB/step
// through one CU's LDS + 390cy bank conflicts + per-step 8-wave barrier);
// end step ~420 ns with 1 compute wave/SIMD. Balance E*t_e = M*t_m ->
// M = 0.13*(len-1). End blocks idle waves 4-7 (barrier-only loop) instead of
// duplicating work — duplication doubled per-SIMD VALU/trans load for nothing.
//
// RULE-#20 NOTE (the rounds-3..7 1-GB-write bug): every array here is indexed
// ONLY with compile-time constants (after unroll). Round 3 introduced
// `int g = isF ? gg : GRP-1-gg;` as a prefetch array index — a RUNTIME index —
// which turned the prefetch arrays into scratch allocas (~1 GB HBM writes per
// dispatch, unaffected by __launch_bounds__). Do not reintroduce.
__global__ __launch_bounds__(512, 1) void scan_kernel(
    const float* __restrict__ em, const void* __restrict__ maskp,
    const int* __restrict__ tags, const void* __restrict__ forb,
    const float* __restrict__ trans,
    const float* __restrict__ startt, const float* __restrict__ endt,
    double* __restrict__ CdW, float* __restrict__ pendW,
    float* __restrict__ uMW, double* __restrict__ lsW,
    unsigned short* __restrict__ Tws, double* __restrict__ postout)
{
    const int t = threadIdx.x;
    const int w = t >> 6;          // wave 0..7
    const int lane = t & 63;
    const int q = lane >> 4;       // quad 0..3
    const int c = lane & 15;       // MFMA n-column
    const int bid = blockIdx.x;

    __shared__ __align__(16) ShU sh;

    const int mode = detect_mode(maskp);

    const bool isEnd = (bid < 2 * BB);
    const bool isF = (bid < BB);
    const int seg = isEnd ? 0 : (bid - 2 * BB);
    const int b = isEnd ? (isF ? bid : bid - BB) : (seg >> 1);
    const int half = seg & 1;

    // ---- length of this batch (contiguous mask prefix) ----
    {
        int cnt = 0;
        for (int s = t; s < SS; s += 512) cnt += mask_at(maskp, mode, (size_t)b * SS + s);
        #pragma unroll
        for (int off = 32; off >= 1; off >>= 1) cnt += __shfl_xor(cnt, off);
        if (lane == 0) sh.e.redi[w] = cnt;
    }
    __syncthreads();
    int len = 0;
    #pragma unroll
    for (int i = 0; i < 8; ++i) len += sh.e.redi[i];
    __syncthreads();   // everyone done reading redi before LDS reuse

    // ---- split points: balanced to measured t_m/t_e ~ 2.9 -> M = 0.13*(len-1) ----
    const int M  = ((len - 1) * 13) / 100;         // mid segment steps (each)
    const int E1 = ((len - 1) - 2 * M + 1) >> 1;   // fwd steps
    const int q1 = E1;
    const int q2 = q1 + M;
    const int q3 = q2 + M;
    const int E2 = (len - 1) - q3;                 // bwd steps

    const float* emB = em + (size_t)b * SS * TT;

    if (isEnd) {
        // =================== END SEGMENTS (matvec chains) ===================
        // Round-2-proven structure. Waves 0-3 compute (1 wave/SIMD); waves 4-7
        // only match the per-step barrier count (idle loop) — duplicating the
        // work (rounds 6-8) doubled per-SIMD VALU/trans load for zero benefit.
        const int w4 = w & 3;
        const int steps = isF ? q1 : E2;

        // init: fwd u0 = exp(start + em[0] - M0); bwd d_{len-1} = exp(end + em[len-1] - M0)
        if (t < 16) {
            const float* base = isF ? startt : endt;
            const float* emI  = emB + (isF ? 0 : (size_t)(len - 1) * TT);
            float a[8]; float mx = -1e30f;
            #pragma unroll
            for (int jj = 0; jj < 8; ++jj) {
                int j = t * 8 + jj;
                a[jj] = base[j] + emI[j];
                mx = fmaxf(mx, a[jj]);
            }
            mx = fmaxf(mx, __shfl_xor(mx, 1)); mx = fmaxf(mx, __shfl_xor(mx, 2));
            mx = fmaxf(mx, __shfl_xor(mx, 4)); mx = fmaxf(mx, __shfl_xor(mx, 8));
            union { __bf16 h[8]; uint4 v; } pk;
            #pragma unroll
            for (int jj = 0; jj < 8; ++jj) pk.h[jj] = (__bf16)__expf(a[jj] - mx);
            *(uint4*)&sh.e.uS[0][t * 8] = pk.v;
            if (t == 0) sh.e.Minit = mx;
        }
        __syncthreads();

        double Cd = (double)sh.e.Minit;
        float pending = 1.0f;
        int cur = 0;

        if (w < 4) {
            // fwd: A[m=c][k=8q+jj] of tile (2w4+ml, kt) = E[32kt+8q+jj][32w4+16ml+c]
            // bwd: A[m=c][k=8q+jj] of tile (2w4+ml, kt) = E[32w4+16ml+c][32kt+8q+jj]
            bf16x8 afrag[2][4];
            #pragma unroll
            for (int ml = 0; ml < 2; ++ml) {
                #pragma unroll
                for (int kt = 0; kt < 4; ++kt) {
                    #pragma unroll
                    for (int jj = 0; jj < 8; ++jj) {
                        int row = isF ? (32 * kt + 8 * q + jj) : (32 * w4 + 16 * ml + c);
                        int col = isF ? (32 * w4 + 16 * ml + c) : (32 * kt + 8 * q + jj);
                        size_t idx = (size_t)row * TT + col;
                        afrag[ml][kt][jj] = mask_at(forb, mode, idx) ? (__bf16)0.f
                                                                     : (__bf16)__expf(trans[idx]);
                    }
                }
            }

            const int tag0 = 32 * w4 + 4 * q;
            const int tag1 = tag0 + 16;

            auto stepfn = [&](float4 e0, float4 e1, bool ren, bool scaleEm) {
                const __bf16* ub = &sh.e.uS[cur][0];
                bf16x8 bf0 = *(const bf16x8*)(ub + 8 * q);
                bf16x8 bf1 = *(const bf16x8*)(ub + 32 + 8 * q);
                bf16x8 bf2 = *(const bf16x8*)(ub + 64 + 8 * q);
                bf16x8 bf3 = *(const bf16x8*)(ub + 96 + 8 * q);

                float sc00 = (scaleEm ? __expf(e0.x) : 1.0f) * pending;
                float sc01 = (scaleEm ? __expf(e0.y) : 1.0f) * pending;
                float sc02 = (scaleEm ? __expf(e0.z) : 1.0f) * pending;
                float sc03 = (scaleEm ? __expf(e0.w) : 1.0f) * pending;
                float sc10 = (scaleEm ? __expf(e1.x) : 1.0f) * pending;
                float sc11 = (scaleEm ? __expf(e1.y) : 1.0f) * pending;
                float sc12 = (scaleEm ? __expf(e1.z) : 1.0f) * pending;
                float sc13 = (scaleEm ? __expf(e1.w) : 1.0f) * pending;

                f32x4 aA0 = {0,0,0,0}, aB0 = {0,0,0,0}, aA1 = {0,0,0,0}, aB1 = {0,0,0,0};
                aA0 = __builtin_amdgcn_mfma_f32_16x16x32_bf16(afrag[0][0], bf0, aA0, 0, 0, 0);
                aA1 = __builtin_amdgcn_mfma_f32_16x16x32_bf16(afrag[1][0], bf0, aA1, 0, 0, 0);
                aB0 = __builtin_amdgcn_mfma_f32_16x16x32_bf16(afrag[0][2], bf2, aB0, 0, 0, 0);
                aB1 = __builtin_amdgcn_mfma_f32_16x16x32_bf16(afrag[1][2], bf2, aB1, 0, 0, 0);
                aA0 = __builtin_amdgcn_mfma_f32_16x16x32_bf16(afrag[0][1], bf1, aA0, 0, 0, 0);
                aA1 = __builtin_amdgcn_mfma_f32_16x16x32_bf16(afrag[1][1], bf1, aA1, 0, 0, 0);
                aB0 = __builtin_amdgcn_mfma_f32_16x16x32_bf16(afrag[0][3], bf3, aB0, 0, 0, 0);
                aB1 = __builtin_amdgcn_mfma_f32_16x16x32_bf16(afrag[1][3], bf3, aB1, 0, 0, 0);

                float v00 = (aA0[0] + aB0[0]) * sc00, v01 = (aA0[1] + aB0[1]) * sc01;
                float v02 = (aA0[2] + aB0[2]) * sc02, v03 = (aA0[3] + aB0[3]) * sc03;
                float v10 = (aA1[0] + aB1[0]) * sc10, v11 = (aA1[1] + aB1[1]) * sc11;
                float v12 = (aA1[2] + aB1[2]) * sc12, v13 = (aA1[3] + aB1[3]) * sc13;

                if (c == 0) {
                    union { __bf16 h[4]; uint2 v; } p0, p1;
                    p0.h[0] = (__bf16)v00; p0.h[1] = (__bf16)v01;
                    p0.h[2] = (__bf16)v02; p0.h[3] = (__bf16)v03;
                    p1.h[0] = (__bf16)v10; p1.h[1] = (__bf16)v11;
                    p1.h[2] = (__bf16)v12; p1.h[3] = (__bf16)v13;
                    __bf16* un = &sh.e.uS[cur ^ 1][0];
                    *(uint2*)(un + tag0) = p0.v;
                    *(uint2*)(un + tag1) = p1.v;
                }
                if (ren) {
                    float m = fmaxf(fmaxf(fmaxf(v00, v01), fmaxf(v02, v03)),
                                    fmaxf(fmaxf(v10, v11), fmaxf(v12, v13)));
                    m = fmaxf(m, __shfl_xor(m, 16));
                    m = fmaxf(m, __shfl_xor(m, 32));
                    if (lane == 0) sh.e.wred[w4] = m;
                }
                wg_barrier_lds();
                if (ren) {
                    float4 wm = *(const float4*)sh.e.wred;
                    float Mx = fmaxf(fmaxf(wm.x, wm.y), fmaxf(wm.z, wm.w));
                    pending = 1.0f / Mx;
                    Cd += (double)__logf(Mx);
                } else {
                    pending = 1.0f;
                }
                cur ^= 1;
            };

            // em row at slot s: fwd -> 1+s; bwd -> len-2-s. Prefetch GRP ahead.
            // STATIC array index g only (rule #20).
            int k = 0;
            float4 emc0[GRP], emc1[GRP];
            #pragma unroll
            for (int g = 0; g < GRP; ++g) {
                int kk = isF ? (1 + g) : (len - 2 - g);
                kk = kk < SS ? kk : SS - 1;
                kk = kk > 0 ? kk : 0;
                emc0[g] = *(const float4*)(emB + (size_t)kk * TT + tag0);
                emc1[g] = *(const float4*)(emB + (size_t)kk * TT + tag1);
            }

            while (k + GRP <= steps) {
                float4 emn0[GRP], emn1[GRP];
                #pragma unroll
                for (int g = 0; g < GRP; ++g) {
                    int kk = isF ? (1 + k + GRP + g) : (len - 2 - (k + GRP + g));
                    kk = kk < SS ? kk : SS - 1;
                    kk = kk > 0 ? kk : 0;
                    emn0[g] = *(const float4*)(emB + (size_t)kk * TT + tag0);
                    emn1[g] = *(const float4*)(emB + (size_t)kk * TT + tag1);
                }
                #pragma unroll
                for (int g = 0; g < GRP; ++g)
                    stepfn(emc0[g], emc1[g], g == GRP - 1, isF || (k + g != steps - 1));
                #pragma unroll
                for (int g = 0; g < GRP; ++g) { emc0[g] = emn0[g]; emc1[g] = emn1[g]; }
                k += GRP;
            }
            while (k < steps) {
                int kk = isF ? (1 + k) : (len - 2 - k);
                float4 e0 = *(const float4*)(emB + (size_t)kk * TT + tag0);
                float4 e1 = *(const float4*)(emB + (size_t)kk * TT + tag1);
                stepfn(e0, e1, true, isF || (k != steps - 1));
                ++k;
            }
        } else {
            // waves 4-7: match barrier count only (one wg_barrier_lds per step)
            for (int k = 0; k < steps; ++k) wg_barrier_lds();
        }

        // ---- dump state (fwd: alpha_q1 scaled; bwd: gamma_q3 scaled) ----
        __syncthreads();
        // cur/pending valid in waves 0-3; dump threads t<128 are waves 0-1;
        // CdW/pendW written by t==0 (wave 0). steps parity gives cur for idle waves too,
        // but we only read from compute waves' threads.
        if (t < TT) uMW[(size_t)(isF ? 0 : BB) * TT + (size_t)b * TT + t] = (float)sh.e.uS[cur][t];
        if (t == 0) { CdW[(isF ? 0 : BB) + b] = Cd; pendW[(isF ? 0 : BB) + b] = pending; }

        // ---- posterior path score (fwd blocks only; 512 threads strided) ----
        if (isF) {
            const int* tg = tags + (size_t)b * SS;
            double local = 0.0; int fcnt = 0;
            for (int kk = 1 + t; kk < len; kk += 512) {
                int tp = tg[kk - 1], tc = tg[kk];
                if (mask_at(forb, mode, (size_t)tp * TT + tc)) fcnt++;
                else local += (double)trans[tp * TT + tc];
                local += (double)emB[(size_t)kk * TT + tc];
            }
            if (t == 0) {
                local += (double)startt[tg[0]] + (double)emB[tg[0]];
                local += (double)endt[tg[len - 1]];
            }
            #pragma unroll
            for (int off = 32; off >= 1; off >>= 1) {
                local += __shfl_xor(local, off);
                fcnt  += __shfl_xor(fcnt, off);
            }
            if (lane == 0) { sh.e.redd[w] = local; sh.e.redc[w] = fcnt; }
            __syncthreads();
            if (t == 0) {
                double tot = 0.0; int fc = 0;
                #pragma unroll
                for (int i = 0; i < 8; ++i) { tot += sh.e.redd[i]; fc += sh.e.redc[i]; }
                postout[b] = tot - 100000.0 * (double)fc;
            }
        }
    } else {
        // =================== MID SEGMENTS (transfer-matrix GEMM chain) ===================
        // Tiling: wave w = (wr = w>>2, wc = w&3); rows 64*wr..+63 (mt=4wr+mi),
        // cols 32*wc+c (ni=0) and +16 (ni=1). af = 4x4 frags = 64 VGPR.
        // XOR swizzle: elem k of col n at n*128 + (k ^ ((n&7)<<3)).
        // Renorm: per-column max from the freshly LOADED B-frags, fully in-wave.
        const int wr = w >> 2;
        const int wc = w & 3;
        const int ks = half ? q2 : q1;     // steps consume em rows ks+1 .. ks+M
        const int steps = M;
        const int col0 = 32 * wc + c;
        const int col1 = col0 + 16;
        const int base0 = col0 * 128;
        const int base1 = col1 * 128;
        const int sw = (c & 7) << 3;       // (col&7)<<3 — same for col0/col1
        const int rowq = 4 * q;

        // A = E^T: af[mi][kt][jj] = E[32kt+8q+jj][16*(4wr+mi)+c]
        bf16x8 af[4][4];
        #pragma unroll
        for (int mi = 0; mi < 4; ++mi) {
            #pragma unroll
            for (int kt = 0; kt < 4; ++kt) {
                #pragma unroll
                for (int jj = 0; jj < 8; ++jj) {
                    size_t idx = (size_t)(32 * kt + 8 * q + jj) * TT + (16 * (4 * wr + mi) + c);
                    af[mi][kt][jj] = mask_at(forb, mode, idx) ? (__bf16)0.f
                                                              : (__bf16)__expf(trans[idx]);
                }
            }
        }

        // identity init of T[0] (swizzled)
        for (int p = t; p < 8192; p += 512) {
            int n  = p >> 6;
            int k2 = (p & 63) * 2;
            unsigned int v = (k2 == n ? 0x3F80u : 0u) | (k2 + 1 == n ? 0x3F800000u : 0u);
            *(unsigned int*)&sh.m.T[0][n * 128 + (k2 ^ ((n & 7) << 3))] = v;
        }
        __syncthreads();

        double Cdc0 = 0.0, Cdc1 = 0.0;
        int cur = 0;
        int rc = 0;                        // steps since last renorm

        // single-float4 em load: scalar return, no aggregate (rule #20 safe)
        auto lde = [&](int s, int mi) -> float4 {
            int kk = ks + 1 + s; kk = kk < SS ? kk : SS - 1;
            return *(const float4*)(emB + (size_t)kk * TT + 16 * (4 * wr + mi) + rowq);
        };

        auto midstep = [&](float4 ev0, float4 ev1, float4 ev2, float4 ev3) {
            const float4 ev[4] = {ev0, ev1, ev2, ev3};   // static-index only below
            const __bf16* Tc = &sh.m.T[cur][0];
            bf16x8 bf0[4], bf1[4];
            #pragma unroll
            for (int kt = 0; kt < 4; ++kt) {
                int eo = (32 * kt + 8 * q) ^ sw;
                bf0[kt] = *(const bf16x8*)(Tc + base0 + eo);
                bf1[kt] = *(const bf16x8*)(Tc + base1 + eo);
            }

            bool ren;
            if (rc == GRP) { ren = true; rc = 0; } else ren = false;
            ++rc;

            float pend0 = 1.0f, pend1 = 1.0f;
            if (ren) {    // per-column max of the INPUT, from the loaded frags
                float m0 = 0.f, m1 = 0.f;
                #pragma unroll
                for (int kt = 0; kt < 4; ++kt) {
                    #pragma unroll
                    for (int jj = 0; jj < 8; ++jj) {
                        m0 = fmaxf(m0, (float)bf0[kt][jj]);
                        m1 = fmaxf(m1, (float)bf1[kt][jj]);
                    }
                }
                m0 = fmaxf(m0, __shfl_xor(m0, 16)); m0 = fmaxf(m0, __shfl_xor(m0, 32));
                m1 = fmaxf(m1, __shfl_xor(m1, 16)); m1 = fmaxf(m1, __shfl_xor(m1, 32));
                pend0 = 1.0f / m0; pend1 = 1.0f / m1;
                Cdc0 += (double)__logf(m0); Cdc1 += (double)__logf(m1);
            }

            f32x4 acc[4][2];
            #pragma unroll
            for (int mi = 0; mi < 4; ++mi) {
                acc[mi][0] = (f32x4){0.f, 0.f, 0.f, 0.f};
                acc[mi][1] = (f32x4){0.f, 0.f, 0.f, 0.f};
            }
            #pragma unroll
            for (int kt = 0; kt < 4; ++kt) {
                #pragma unroll
                for (int mi = 0; mi < 4; ++mi)
                    acc[mi][0] = __builtin_amdgcn_mfma_f32_16x16x32_bf16(af[mi][kt], bf0[kt], acc[mi][0], 0, 0, 0);
                #pragma unroll
                for (int mi = 0; mi < 4; ++mi)
                    acc[mi][1] = __builtin_amdgcn_mfma_f32_16x16x32_bf16(af[mi][kt], bf1[kt], acc[mi][1], 0, 0, 0);
            }

            __bf16* Tn = &sh.m.T[cur ^ 1][0];
            #pragma unroll
            for (int mi = 0; mi < 4; ++mi) {
                float s0 = __expf(ev[mi].x), s1 = __expf(ev[mi].y);
                float s2 = __expf(ev[mi].z), s3 = __expf(ev[mi].w);
                const int row = 16 * (4 * wr + mi) + rowq;
                const int eo = row ^ sw;
                union { __bf16 h[4]; uint2 u; } pk0, pk1;
                pk0.h[0] = (__bf16)(acc[mi][0][0] * s0 * pend0);
                pk0.h[1] = (__bf16)(acc[mi][0][1] * s1 * pend0);
                pk0.h[2] = (__bf16)(acc[mi][0][2] * s2 * pend0);
                pk0.h[3] = (__bf16)(acc[mi][0][3] * s3 * pend0);
                pk1.h[0] = (__bf16)(acc[mi][1][0] * s0 * pend1);
                pk1.h[1] = (__bf16)(acc[mi][1][1] * s1 * pend1);
                pk1.h[2] = (__bf16)(acc[mi][1][2] * s2 * pend1);
                pk1.h[3] = (__bf16)(acc[mi][1][3] * s3 * pend1);
                *(uint2*)(Tn + base0 + eo) = pk0.u;
                *(uint2*)(Tn + base1 + eo) = pk1.u;
            }
            wg_barrier_lds();
            cur ^= 1;
        };

        // 2-unrolled main loop, depth-2 em prefetch in NAMED float4s (no arrays)
        float4 eA0 = lde(0, 0), eA1 = lde(0, 1), eA2 = lde(0, 2), eA3 = lde(0, 3);
        float4 eB0 = lde(1, 0), eB1 = lde(1, 1), eB2 = lde(1, 2), eB3 = lde(1, 3);
        int s = 0;
        while (s + 2 <= steps) {
            midstep(eA0, eA1, eA2, eA3);
            eA0 = lde(s + 2, 0); eA1 = lde(s + 2, 1); eA2 = lde(s + 2, 2); eA3 = lde(s + 2, 3);
            midstep(eB0, eB1, eB2, eB3);
            eB0 = lde(s + 3, 0); eB1 = lde(s + 3, 1); eB2 = lde(s + 3, 2); eB3 = lde(s + 3, 3);
            s += 2;
        }
        if (s < steps) midstep(eA0, eA1, eA2, eA3);

        __syncthreads();
        // per-column log-scale: true col = stored * exp(ls)
        if (wr == 0 && q == 0) {
            lsW[(size_t)seg * 128 + col0] = Cdc0;
            lsW[(size_t)seg * 128 + col1] = Cdc1;
        }
        // dump T (unswizzle) to workspace, bf16 raw
        for (int p = t; p < 8192; p += 512) {
            int n  = p >> 6;
            int k2 = (p & 63) * 2;
            unsigned int v = *(const unsigned int*)&sh.m.T[cur][n * 128 + (k2 ^ ((n & 7) << 3))];
            *(unsigned int*)&Tws[(size_t)seg * 16384 + (size_t)n * 128 + k2] = v;
        }
    }
}

// ---- combine: z[b] = Cf + lpf + K1 + K2 + Cb + lpb + log( sum_i s_i*gamma_i ) ----
__global__ __launch_bounds__(128) void comb_kernel(
    const double* __restrict__ CdW, const float* __restrict__ pendW,
    const float* __restrict__ uMW, const double* __restrict__ lsW,
    const unsigned short* __restrict__ Tws, double* __restrict__ zarr)
{
    const int b = blockIdx.x, i = threadIdx.x;
    __shared__ double wv[128];
    __shared__ double red[128];

    // stage 1: w_n = x_n * exp(lsA_n - K1)
    double lsA = lsW[(size_t)(2 * b) * 128 + i];
    float  xf  = uMW[(size_t)b * 128 + i];
    double a1  = (xf > 0.f) ? lsA + log((double)xf) : -1e300;
    red[i] = a1; __syncthreads();
    for (int sdel = 64; sdel >= 1; sdel >>= 1) {
        if (i < sdel) red[i] = fmax(red[i], red[i + sdel]);
        __syncthreads();
    }
    double K1 = red[0]; __syncthreads();
    wv[i] = (xf > 0.f) ? exp(a1 - K1) : 0.0; __syncthreads();

    const unsigned short* TA = Tws + (size_t)(2 * b) * 16384;
    double y = 0.0;
    for (int n = 0; n < 128; ++n) {
        unsigned int u = ((unsigned int)TA[(size_t)n * 128 + i]) << 16;
        y += (double)__uint_as_float(u) * wv[n];
    }
    __syncthreads();

    // stage 2: w2_n = y_n * exp(lsB_n - K2)
    double lsB = lsW[(size_t)(2 * b + 1) * 128 + i];
    double a2  = (y > 0.0) ? lsB + log(y) : -1e300;
    red[i] = a2; __syncthreads();
    for (int sdel = 64; sdel >= 1; sdel >>= 1) {
        if (i < sdel) red[i] = fmax(red[i], red[i + sdel]);
        __syncthreads();
    }
    double K2 = red[0]; __syncthreads();
    wv[i] = (y > 0.0) ? exp(a2 - K2) : 0.0; __syncthreads();

    const unsigned short* TB = Tws + (size_t)(2 * b + 1) * 16384;
    double s = 0.0;
    for (int n = 0; n < 128; ++n) {
        unsigned int u = ((unsigned int)TB[(size_t)n * 128 + i]) << 16;
        s += (double)__uint_as_float(u) * wv[n];
    }
    double g = (double)uMW[(size_t)(BB + b) * 128 + i];
    red[i] = s * g; __syncthreads();
    for (int sdel = 64; sdel >= 1; sdel >>= 1) {
        if (i < sdel) red[i] += red[i + sdel];
        __syncthreads();
    }
    if (i == 0) {
        zarr[b] = CdW[b] + log((double)pendW[b])
                + CdW[BB + b] + log((double)pendW[BB + b])
                + K1 + K2 + log(red[0]);
    }
}

// ---- nll = mean(post) - mean(z) ----
__global__ void fin_kernel(const double* __restrict__ z, const double* __restrict__ post,
                           float* __restrict__ out) {
    int t = threadIdx.x; // 64 threads, 1 wave
    double pv = post[t];
    double zv = z[t];
    #pragma unroll
    for (int off = 32; off >= 1; off >>= 1) {
        pv += __shfl_xor(pv, off);
        zv += __shfl_xor(zv, off);
    }
    if (t == 0) out[0] = (float)((pv - zv) / (double)BB);
}

extern "C" void kernel_launch(void* const* d_in, const int* in_sizes, int n_in,
                              void* d_out, int out_size, void* d_ws, size_t ws_size,
                              hipStream_t stream) {
    const float* em     = (const float*)d_in[0];
    const void*  maskp  = d_in[1];
    const int*   tags   = (const int*)d_in[2];
    const void*  forb   = d_in[3];
    const float* trans  = (const float*)d_in[4];
    const float* startt = (const float*)d_in[5];
    const float* endt   = (const float*)d_in[6];

    // workspace: ~4.4 MB (layout proven in round 3)
    double* post  = (double*)d_ws;                     // 64
    double* zarr  = post + BB;                         // 64
    double* CdW   = zarr + BB;                         // 128 (fwd | bwd)
    double* lsW   = CdW + 2 * BB;                      // 128 segs x 128 cols
    float*  pendW = (float*)(lsW + 128 * 128);         // 128
    float*  uMW   = pendW + 2 * BB;                    // 128 x 128 (fwd states | bwd states)
    unsigned short* Tws = (unsigned short*)(uMW + 128 * 128); // 128 segs x 128 x 128 bf16

    scan_kernel<<<4 * BB, 512, 0, stream>>>(em, maskp, tags, forb, trans, startt, endt,
                                            CdW, pendW, uMW, lsW, Tws, post);
    comb_kernel<<<BB, 128, 0, stream>>>(CdW, pendW, uMW, lsW, Tws, zarr);
    fin_kernel<<<1, 64, 0, stream>>>(zarr, post, (float*)d_out);
}